// Round 9
// baseline (570.614 us; speedup 1.0000x reference)
//
#include <hip/hip_runtime.h>
#include <stdint.h>

#define TT 2048      // T
#define CC 2048      // C
#define NHEAD 16
#define HD 128
#define NB 4         // batch
#define MTOT (NB*TT) // 8192
#define KD 2048      // GEMM K (both projections)
#define NT 32        // K tiles of 64

typedef __attribute__((ext_vector_type(8))) short bf16x8;
typedef __attribute__((ext_vector_type(4))) float f32x4;

__device__ __forceinline__ unsigned short f2bf(float f) {
  unsigned u = __float_as_uint(f);
  u += 0x7FFF + ((u >> 16) & 1);
  return (unsigned short)(u >> 16);
}
__device__ __forceinline__ float bf2f(unsigned short h) {
  return __uint_as_float(((unsigned)h) << 16);
}

__device__ __forceinline__ void gl_lds16(const unsigned short* g, short* l) {
  __builtin_amdgcn_global_load_lds(
      (const __attribute__((address_space(1))) void*)(g),
      (__attribute__((address_space(3))) void*)(l), 16, 0, 0);
}

#define MFMA16(a, b, c) __builtin_amdgcn_mfma_f32_16x16x32_bf16((a), (b), (c), 0, 0, 0)

#define PRE_MFMA() do { \
  __builtin_amdgcn_s_barrier(); \
  asm volatile("s_waitcnt lgkmcnt(0)" ::: "memory"); \
  __builtin_amdgcn_s_setprio(1); \
} while(0)
#define POST_MFMA() do { \
  __builtin_amdgcn_s_setprio(0); \
  __builtin_amdgcn_s_barrier(); \
  __builtin_amdgcn_sched_barrier(0); \
} while(0)

// ---------------- fp32 -> bf16 cast ----------------
__global__ void k_f2b(const float* __restrict__ in, unsigned short* __restrict__ out, int n4) {
  int i = blockIdx.x * 256 + threadIdx.x;
  if (i >= n4) return;
  float4 v = reinterpret_cast<const float4*>(in)[i];
  ushort4 o;
  o.x = f2bf(v.x); o.y = f2bf(v.y); o.z = f2bf(v.z); o.w = f2bf(v.w);
  reinterpret_cast<ushort4*>(out)[i] = o;
}

// ---------------- RoPE table (fp64 on device; matches np ref closely) ----------------
__global__ void k_rope_tab(float* __restrict__ tab) {
  int t = blockIdx.x, i = threadIdx.x;  // 2048 x 64
  double inv = exp2(-(double)i * (13.287712379549449062 / 64.0)); // 10000^(-i/64)
  double ang = (double)t * inv;
  tab[(t*64 + i)*2 + 0] = (float)cos(ang);
  tab[(t*64 + i)*2 + 1] = (float)sin(ang);
}

// ================= 256x256 8-wave kk-split GEMM core (unchanged, round 4) =================
__device__ __forceinline__ void gemm256_core(
    const unsigned short* __restrict__ Ag,
    const unsigned short* __restrict__ Bg,
    int m0, int n0, short* lds, f32x4 (&acc)[8][4])
{
  const int tid = threadIdx.x;
  const int wid = tid >> 6, lane = tid & 63;
  const int wm = wid >> 2, wn = wid & 3;
  const int r15 = lane & 15, hi4 = lane >> 4;
  const int srow = wid*8 + (lane >> 3);
  const int schunk = (lane & 7) ^ (lane >> 3);

  const f32x4 fz = {0.f, 0.f, 0.f, 0.f};
#pragma unroll
  for (int i = 0; i < 8; i++)
#pragma unroll
    for (int j = 0; j < 4; j++) acc[i][j] = fz;

  int aoff0[8];
#pragma unroll
  for (int mi = 0; mi < 8; mi++) {
    int row = wm*128 + mi*16 + r15;
    aoff0[mi] = row*64 + ((hi4 ^ (row & 7))*8);
  }
  int boff0[4];
#pragma unroll
  for (int ni = 0; ni < 4; ni++) {
    int row = wn*64 + ni*16 + r15;
    boff0[ni] = row*64 + ((hi4 ^ (row & 7))*8);
  }

#define STAGE(G, L, GROW0, KT) do { \
    gl_lds16((G) + (size_t)((GROW0) + srow)*KD + (KT) + schunk*8, (L) + wid*512); \
    gl_lds16((G) + (size_t)((GROW0) + 64 + srow)*KD + (KT) + schunk*8, (L) + 4096 + wid*512); \
  } while(0)

  STAGE(Ag, lds,                        m0,       0);
  STAGE(Ag, lds + 8192,                 m0 + 128, 0);
  STAGE(Bg, lds + 32768,                n0,       0);
  STAGE(Bg, lds + 32768 + 8192,         n0 + 128, 0);
  STAGE(Bg, lds + 32768 + 16384,        n0,       64);
  STAGE(Bg, lds + 32768 + 16384 + 8192, n0 + 128, 64);
  asm volatile("s_waitcnt vmcnt(4)" ::: "memory");
  __builtin_amdgcn_s_barrier();
  __builtin_amdgcn_sched_barrier(0);

#pragma unroll 1
  for (int t = 0; t < NT; t++) {
    const int db = t & 1;
    short* Ab = lds + db*16384;
    short* Bb = lds + 32768 + db*16384;
    short* An = lds + (db ^ 1)*16384;
    const int kt = t*64;
    const bool stA = (t < NT - 1);
    const bool stB = (t < NT - 2);

    bf16x8 a[8], b[4][2];
    // ---- phase 0: kk=0 ----
#pragma unroll
    for (int mi = 0; mi < 8; mi++)
      a[mi] = *reinterpret_cast<const bf16x8*>(Ab + aoff0[mi]);
#pragma unroll
    for (int ni = 0; ni < 4; ni++) {
      b[ni][0] = *reinterpret_cast<const bf16x8*>(Bb + boff0[ni]);
      b[ni][1] = *reinterpret_cast<const bf16x8*>(Bb + (boff0[ni] ^ 32));
    }
    if (stA) {
      STAGE(Ag, An,        m0,       kt + 64);
      STAGE(Ag, An + 8192, m0 + 128, kt + 64);
    }
    PRE_MFMA();
#pragma unroll
    for (int mi = 0; mi < 8; mi++)
#pragma unroll
      for (int ni = 0; ni < 4; ni++)
        acc[mi][ni] = MFMA16(a[mi], b[ni][0], acc[mi][ni]);
    POST_MFMA();

    // ---- phase 1: kk=1 ----
#pragma unroll
    for (int mi = 0; mi < 8; mi++)
      a[mi] = *reinterpret_cast<const bf16x8*>(Ab + (aoff0[mi] ^ 32));
    if (stB) {
      STAGE(Bg, Bb,        n0,       kt + 128);
      STAGE(Bg, Bb + 8192, n0 + 128, kt + 128);
    }
    if (t >= NT - 2) asm volatile("s_waitcnt vmcnt(0)" ::: "memory");
    else             asm volatile("s_waitcnt vmcnt(4)" ::: "memory");
    PRE_MFMA();
#pragma unroll
    for (int mi = 0; mi < 8; mi++)
#pragma unroll
      for (int ni = 0; ni < 4; ni++)
        acc[mi][ni] = MFMA16(a[mi], b[ni][1], acc[mi][ni]);
    POST_MFMA();
  }
#undef STAGE
}

// ---------------- QKV projection + scatter (q,k -> [B,H,T,D]; v -> [B,H,D,T]) ----------------
__global__ __launch_bounds__(512, 2) void k_qkv(
    const unsigned short* __restrict__ xb,
    const unsigned short* __restrict__ wab,
    unsigned short* __restrict__ qr,
    unsigned short* __restrict__ kr,
    unsigned short* __restrict__ vt)
{
  __shared__ __align__(16) short lds[65536];
  f32x4 acc[8][4];
  int bid = blockIdx.x;                      // 768 blocks = 32 mt x 24 nt
  int swz = (bid & 7)*96 + (bid >> 3);       // bijective XCD swizzle (768 % 8 == 0)
  int m0 = (swz / 24)*256, n0 = (swz % 24)*256;
  gemm256_core(xb, wab, m0, n0, lds, acc);

  int tid = threadIdx.x, wid = tid >> 6, lane = tid & 63;
  int wm = wid >> 2, wn = wid & 3, r15 = lane & 15, hi4 = lane >> 4;
  int nw0 = n0 + wn*64;
  int which = nw0 >> 11;            // 0=q, 1=k, 2=v
  int h = (nw0 & 2047) >> 7;        // head (wave's 64 cols lie in one head)
#pragma unroll
  for (int mi = 0; mi < 8; mi++) {
    int m_base = m0 + wm*128 + mi*16 + hi4*4;
    int b = m_base >> 11;
    int t0 = m_base & (TT - 1);
#pragma unroll
    for (int ni = 0; ni < 4; ni++) {
      int d = (nw0 & 127) + ni*16 + r15;
      if (which == 2) {
        ushort4 pv;
        pv.x = f2bf(acc[mi][ni][0]); pv.y = f2bf(acc[mi][ni][1]);
        pv.z = f2bf(acc[mi][ni][2]); pv.w = f2bf(acc[mi][ni][3]);
        *reinterpret_cast<ushort4*>(vt + ((size_t)((b*NHEAD + h)*HD + d))*TT + t0) = pv;
      } else {
        unsigned short* dst = (which == 0) ? qr : kr;
        size_t base = ((size_t)(b*NHEAD + h)*TT + t0)*HD + d;
#pragma unroll
        for (int r = 0; r < 4; r++) dst[base + (size_t)r*HD] = f2bf(acc[mi][ni][r]);
      }
    }
  }
}

// ---------------- output projection ----------------
__global__ __launch_bounds__(512, 2) void k_proj(
    const unsigned short* __restrict__ yb,
    const unsigned short* __restrict__ wpb,
    float* __restrict__ out)
{
  __shared__ __align__(16) short lds[65536];
  f32x4 acc[8][4];
  int bid = blockIdx.x;                      // 256 blocks = 32 mt x 8 nt
  int swz = (bid & 7)*32 + (bid >> 3);
  int m0 = (swz / 8)*256, n0 = (swz % 8)*256;
  gemm256_core(yb, wpb, m0, n0, lds, acc);

  int tid = threadIdx.x, wid = tid >> 6, lane = tid & 63;
  int wm = wid >> 2, wn = wid & 3, r15 = lane & 15, hi4 = lane >> 4;
  int nw0 = n0 + wn*64;
#pragma unroll
  for (int mi = 0; mi < 8; mi++) {
    int m = m0 + wm*128 + mi*16 + hi4*4;
#pragma unroll
    for (int ni = 0; ni < 4; ni++) {
      int n = nw0 + ni*16 + r15;
#pragma unroll
      for (int r = 0; r < 4; r++)
        out[(size_t)(m + r)*CC + n] = acc[mi][ni][r];
    }
  }
}

// ---------------- in-place RoPE on q,k ----------------
__global__ void k_rope_apply(unsigned int* __restrict__ q32, unsigned int* __restrict__ k32,
                             const float* __restrict__ tab) {
  int i = blockIdx.x * 256 + threadIdx.x;   // over B*H*T*64
  int ii = i & 63;
  int t = (i >> 6) & (TT - 1);
  float c = tab[(t*64 + ii)*2], s = tab[(t*64 + ii)*2 + 1];
  unsigned qv = q32[i];
  float q1 = bf2f((unsigned short)qv), q2 = bf2f((unsigned short)(qv >> 16));
  unsigned short lo = f2bf(q1*c - q2*s), hi = f2bf(q1*s + q2*c);
  q32[i] = (unsigned)lo | ((unsigned)hi << 16);
  unsigned kv = k32[i];
  float k1 = bf2f((unsigned short)kv), k2 = bf2f((unsigned short)(kv >> 16));
  lo = f2bf(k1*c - k2*s); hi = f2bf(k1*s + k2*c);
  k32[i] = (unsigned)lo | ((unsigned)hi << 16);
}

// ---------------- causal flash attention, 2 q-subtiles/wave, time-multiplexed single buffer ----
// grid: 1024 blocks = 64 bh x 16 q-blocks of 128 rows; heavy blocks (large qb) FIRST
//       -> tail is the light blocks. 48KB LDS + ~160 VGPR -> 3 blocks/CU.
// Schedule (2 barriers/tile, both staging latencies hidden):
//   QK^T(K) | barrier A | async-stage K(t+1)   [hides under softmax+PV]
//   softmax+PV(V)       | barrier B (vmcnt drain completes K(t+1))
//                       | async-stage V(t+1)   [hides under next QK^T]
// K/V staged via global_load_lds, inverse-swizzled per-lane source (rule 21).
__global__ __launch_bounds__(256) void k_attn(
    const unsigned short* __restrict__ qr,
    const unsigned short* __restrict__ kr,
    const unsigned short* __restrict__ vt,
    unsigned short* __restrict__ yb)
{
  __shared__ __align__(16) short Ks[64*128];   // [kv][d], chunk-XOR swizzled
  __shared__ __align__(16) short Vs[128*64];   // [d][kv], chunk-XOR swizzled
  __shared__ short Pw[4*32*64];                // per-wave P (16KB)
  int bid = blockIdx.x;
  int bh = bid & 63, qb = 15 - (bid >> 6);     // heavy-first
  int tid = threadIdx.x, w = tid >> 6, lane = tid & 63;
  int r15 = lane & 15, hi4 = lane >> 4;
  const unsigned short* qg = qr + (size_t)bh*TT*HD;
  const unsigned short* kg = kr + (size_t)bh*TT*HD;
  const unsigned short* vg = vt + (size_t)bh*HD*TT;
  const f32x4 fz = {0.f,0.f,0.f,0.f};
  const float scale = 0.08838834764831845f; // 1/sqrt(128)
  int b = bh >> 4, h = bh & 15;

  // per-lane INVERSE-swizzled global source offsets (elements):
  int ksoff[4], vsoff[4];
#pragma unroll
  for (int i = 0; i < 4; i++) {
    int rK = (w*4 + i)*4 + (lane >> 4);
    int cK = (lane & 15) ^ (rK & 7);
    ksoff[i] = rK*HD + cK*8;
    int dV = (w*4 + i)*8 + (lane >> 3);
    int cV = (lane & 7) ^ (dV & 7);
    vsoff[i] = dV*TT + cV*8;
  }

#define STAGE_K(KV0) do { \
    _Pragma("unroll") \
    for (int i_ = 0; i_ < 4; i_++) \
      gl_lds16(kg + (size_t)(KV0)*HD + ksoff[i_], &Ks[(w*4 + i_)*512]); \
  } while(0)
#define STAGE_V(KV0) do { \
    _Pragma("unroll") \
    for (int i_ = 0; i_ < 4; i_++) \
      gl_lds16(vg + (KV0) + vsoff[i_], &Vs[(w*4 + i_)*512]); \
  } while(0)

  int qlo0 = qb*128 + w*16, qlo1 = qlo0 + 64;
  bf16x8 qf0[4], qf1[4];
  {
    int q0 = qlo0 + r15, q1 = qlo1 + r15;
#pragma unroll
    for (int kk = 0; kk < 4; kk++) {
      qf0[kk] = *reinterpret_cast<const bf16x8*>(qg + (size_t)q0*HD + kk*32 + hi4*8);
      qf1[kk] = *reinterpret_cast<const bf16x8*>(qg + (size_t)q1*HD + kk*32 + hi4*8);
    }
  }
  f32x4 ao0[8], ao1[8];
#pragma unroll
  for (int i = 0; i < 8; i++) { ao0[i] = fz; ao1[i] = fz; }
  float mrow0[4], lsum0[4], mrow1[4], lsum1[4];
#pragma unroll
  for (int r = 0; r < 4; r++) {
    mrow0[r] = -3.0e38f; lsum0[r] = 0.f;
    mrow1[r] = -3.0e38f; lsum1[r] = 0.f;
  }
  int ntiles = 2*qb + 2;

  // prologue: stage tile 0 (K and V), drain
  STAGE_K(0);
  STAGE_V(0);
  __syncthreads();

#pragma unroll 1
  for (int it = 0; it < ntiles; ++it) {
    int kv0 = it*64;
    bool more = (it + 1 < ntiles);
    bool full = (kv0 + 63 <= qlo0);   // wave-uniform: tile strictly below diagonal
    // ---- QK^T both subtiles, shared K fragments ----
    f32x4 s0[4], s1[4];
    __builtin_amdgcn_s_setprio(1);
#pragma unroll
    for (int n = 0; n < 4; n++) {
      s0[n] = fz; s1[n] = fz;
#pragma unroll
      for (int kk = 0; kk < 4; kk++) {
        int kvr = n*16 + r15;
        int ch = (kk*4 + hi4) ^ (kvr & 7);
        bf16x8 kf = *reinterpret_cast<const bf16x8*>((const char*)Ks + kvr*256 + ch*16);
        s1[n] = MFMA16(qf1[kk], kf, s1[n]);
        s0[n] = MFMA16(qf0[kk], kf, s0[n]);
      }
    }
    __builtin_amdgcn_s_setprio(0);
    // ---- barrier A: all waves done reading K; then refill K async ----
    __syncthreads();
    if (more) STAGE_K(kv0 + 64);
    // ---- softmax sub0 ----
    {
      float p[4][4], rmax[4];
#pragma unroll
      for (int r = 0; r < 4; r++) {
        float mx = -3.0e38f;
#pragma unroll
        for (int n = 0; n < 4; n++) {
          float sv = s0[n][r]*scale;
          if (!full) {
            int kvg = kv0 + n*16 + r15;
            int qgi = qlo0 + hi4*4 + r;
            sv = (kvg <= qgi) ? sv : -3.0e38f;
          }
          p[n][r] = sv;
          mx = fmaxf(mx, sv);
        }
        rmax[r] = mx;
      }
#pragma unroll
      for (int mm = 1; mm < 16; mm <<= 1)
#pragma unroll
        for (int r = 0; r < 4; r++) rmax[r] = fmaxf(rmax[r], __shfl_xor(rmax[r], mm));
      bool ng = (rmax[0] <= mrow0[0] + 8.f) && (rmax[1] <= mrow0[1] + 8.f)
             && (rmax[2] <= mrow0[2] + 8.f) && (rmax[3] <= mrow0[3] + 8.f);
      bool defer = __all(ng);
      float alpha[4];
#pragma unroll
      for (int r = 0; r < 4; r++) {
        if (defer) { alpha[r] = 1.f; }
        else {
          float mnew = fmaxf(mrow0[r], rmax[r]);
          alpha[r] = __expf(mrow0[r] - mnew);
          mrow0[r] = mnew;
        }
      }
      float rsum[4];
#pragma unroll
      for (int r = 0; r < 4; r++) {
        float sum = 0.f;
#pragma unroll
        for (int n = 0; n < 4; n++) {
          float pv = __expf(p[n][r] - mrow0[r]);
          p[n][r] = pv; sum += pv;
        }
        rsum[r] = sum;
      }
#pragma unroll
      for (int mm = 1; mm < 16; mm <<= 1)
#pragma unroll
        for (int r = 0; r < 4; r++) rsum[r] += __shfl_xor(rsum[r], mm);
#pragma unroll
      for (int r = 0; r < 4; r++) lsum0[r] = lsum0[r]*alpha[r] + rsum[r];
      if (!defer) {
#pragma unroll
        for (int i = 0; i < 8; i++)
#pragma unroll
          for (int r = 0; r < 4; r++) ao0[i][r] *= alpha[r];
      }
#pragma unroll
      for (int r = 0; r < 4; r++) {
        int prow = hi4*4 + r;
#pragma unroll
        for (int n = 0; n < 4; n++) {
          int col = n*16 + r15;
          Pw[w*2048 + prow*64 + (col ^ ((prow & 7) << 3))] = (short)f2bf(p[n][r]);
        }
      }
    }
    // ---- softmax sub1 ----
    {
      float p[4][4], rmax[4];
#pragma unroll
      for (int r = 0; r < 4; r++) {
        float mx = -3.0e38f;
#pragma unroll
        for (int n = 0; n < 4; n++) {
          float sv = s1[n][r]*scale;
          if (!full) {
            int kvg = kv0 + n*16 + r15;
            int qgi = qlo1 + hi4*4 + r;
            sv = (kvg <= qgi) ? sv : -3.0e38f;
          }
          p[n][r] = sv;
          mx = fmaxf(mx, sv);
        }
        rmax[r] = mx;
      }
#pragma unroll
      for (int mm = 1; mm < 16; mm <<= 1)
#pragma unroll
        for (int r = 0; r < 4; r++) rmax[r] = fmaxf(rmax[r], __shfl_xor(rmax[r], mm));
      bool ng = (rmax[0] <= mrow1[0] + 8.f) && (rmax[1] <= mrow1[1] + 8.f)
             && (rmax[2] <= mrow1[2] + 8.f) && (rmax[3] <= mrow1[3] + 8.f);
      bool defer = __all(ng);
      float alpha[4];
#pragma unroll
      for (int r = 0; r < 4; r++) {
        if (defer) { alpha[r] = 1.f; }
        else {
          float mnew = fmaxf(mrow1[r], rmax[r]);
          alpha[r] = __expf(mrow1[r] - mnew);
          mrow1[r] = mnew;
        }
      }
      float rsum[4];
#pragma unroll
      for (int r = 0; r < 4; r++) {
        float sum = 0.f;
#pragma unroll
        for (int n = 0; n < 4; n++) {
          float pv = __expf(p[n][r] - mrow1[r]);
          p[n][r] = pv; sum += pv;
        }
        rsum[r] = sum;
      }
#pragma unroll
      for (int mm = 1; mm < 16; mm <<= 1)
#pragma unroll
        for (int r = 0; r < 4; r++) rsum[r] += __shfl_xor(rsum[r], mm);
#pragma unroll
      for (int r = 0; r < 4; r++) lsum1[r] = lsum1[r]*alpha[r] + rsum[r];
      if (!defer) {
#pragma unroll
        for (int i = 0; i < 8; i++)
#pragma unroll
          for (int r = 0; r < 4; r++) ao1[i][r] *= alpha[r];
      }
#pragma unroll
      for (int r = 0; r < 4; r++) {
        int prow = 16 + hi4*4 + r;
#pragma unroll
        for (int n = 0; n < 4; n++) {
          int col = n*16 + r15;
          Pw[w*2048 + prow*64 + (col ^ ((prow & 7) << 3))] = (short)f2bf(p[n][r]);
        }
      }
    }
    // ---- PV both subtiles, shared V fragments ----
    __builtin_amdgcn_s_setprio(1);
#pragma unroll
    for (int kk = 0; kk < 2; kk++) {
      int ch = (kk*4 + hi4) ^ (r15 & 7);
      bf16x8 pa0 = *reinterpret_cast<const bf16x8*>((char*)Pw + w*4096 + r15*128 + ch*16);
      bf16x8 pa1 = *reinterpret_cast<const bf16x8*>((char*)Pw + w*4096 + (16 + r15)*128 + ch*16);
#pragma unroll
      for (int ds_ = 0; ds_ < 8; ds_++) {
        int d = ds_*16 + r15;
        int vch = (kk*4 + hi4) ^ (d & 7);
        bf16x8 vf = *reinterpret_cast<const bf16x8*>((const char*)Vs + d*128 + vch*16);
        ao1[ds_] = MFMA16(pa1, vf, ao1[ds_]);
        ao0[ds_] = MFMA16(pa0, vf, ao0[ds_]);
      }
    }
    __builtin_amdgcn_s_setprio(0);
    // ---- barrier B: V readers done + vmcnt drain completes K(t+1); refill V ----
    __syncthreads();
    if (more) STAGE_V(kv0 + 64);
  }
  // ---- epilogue both subtiles ----
#pragma unroll
  for (int r = 0; r < 4; r++) {
    int t0 = qlo0 + hi4*4 + r;
    int t1 = qlo1 + hi4*4 + r;
    float inv0 = 1.f / lsum0[r];
    float inv1 = 1.f / lsum1[r];
    size_t base0 = ((size_t)b*TT + t0)*CC + h*HD + r15;
    size_t base1 = ((size_t)b*TT + t1)*CC + h*HD + r15;
#pragma unroll
    for (int ds_ = 0; ds_ < 8; ds_++) {
      yb[base0 + ds_*16] = f2bf(ao0[ds_][r] * inv0);
      yb[base1 + ds_*16] = f2bf(ao1[ds_][r] * inv1);
    }
  }
#undef STAGE_K
#undef STAGE_V
}

extern "C" void kernel_launch(void* const* d_in, const int* in_sizes, int n_in,
                              void* d_out, int out_size, void* d_ws, size_t ws_size,
                              hipStream_t stream) {
  const float* x  = (const float*)d_in[0];
  const float* wa = (const float*)d_in[1];
  const float* wp = (const float*)d_in[2];
  float* out = (float*)d_out;
  char* ws = (char*)d_ws;
  size_t off = 0;
  unsigned short* xb  = (unsigned short*)(ws + off); off += (size_t)MTOT*CC*2;
  unsigned short* wab = (unsigned short*)(ws + off); off += (size_t)3*CC*CC*2;
  unsigned short* wpb = (unsigned short*)(ws + off); off += (size_t)CC*CC*2;
  unsigned short* qr  = (unsigned short*)(ws + off); off += (size_t)MTOT*CC*2;
  unsigned short* kr  = (unsigned short*)(ws + off); off += (size_t)MTOT*CC*2;
  unsigned short* vt  = (unsigned short*)(ws + off); off += (size_t)MTOT*CC*2;
  unsigned short* yb  = (unsigned short*)(ws + off); off += (size_t)MTOT*CC*2;
  float* tab          = (float*)(ws + off);          off += (size_t)TT*64*2*4;

  k_f2b<<<dim3(16384), dim3(256), 0, stream>>>(x,  xb,  MTOT*CC/4);
  k_f2b<<<dim3(12288), dim3(256), 0, stream>>>(wa, wab, 3*CC*CC/4);
  k_f2b<<<dim3(4096),  dim3(256), 0, stream>>>(wp, wpb, CC*CC/4);
  k_rope_tab<<<dim3(TT), dim3(64), 0, stream>>>(tab);
  k_qkv<<<dim3(768), dim3(512), 0, stream>>>(xb, wab, qr, kr, vt);
  k_rope_apply<<<dim3(32768), dim3(256), 0, stream>>>((unsigned int*)qr, (unsigned int*)kr, tab);
  k_attn<<<dim3(1024), dim3(256), 0, stream>>>(qr, kr, vt, yb);
  k_proj<<<dim3(256), dim3(512), 0, stream>>>(yb, wpb, out);
}

// Round 10
// 494.556 us; speedup vs baseline: 1.1538x; 1.1538x over previous
//
#include <hip/hip_runtime.h>
#include <stdint.h>

#define TT 2048      // T
#define CC 2048      // C
#define NHEAD 16
#define HD 128
#define NB 4         // batch
#define MTOT (NB*TT) // 8192
#define KD 2048      // GEMM K (both projections)
#define NT 32        // K tiles of 64

typedef __attribute__((ext_vector_type(8))) short bf16x8;
typedef __attribute__((ext_vector_type(4))) float f32x4;

__device__ __forceinline__ unsigned short f2bf(float f) {
  unsigned u = __float_as_uint(f);
  u += 0x7FFF + ((u >> 16) & 1);
  return (unsigned short)(u >> 16);
}
__device__ __forceinline__ float bf2f(unsigned short h) {
  return __uint_as_float(((unsigned)h) << 16);
}

__device__ __forceinline__ void gl_lds16(const unsigned short* g, short* l) {
  __builtin_amdgcn_global_load_lds(
      (const __attribute__((address_space(1))) void*)(g),
      (__attribute__((address_space(3))) void*)(l), 16, 0, 0);
}

#define MFMA16(a, b, c) __builtin_amdgcn_mfma_f32_16x16x32_bf16((a), (b), (c), 0, 0, 0)

#define PRE_MFMA() do { \
  __builtin_amdgcn_s_barrier(); \
  asm volatile("s_waitcnt lgkmcnt(0)" ::: "memory"); \
  __builtin_amdgcn_s_setprio(1); \
} while(0)
#define POST_MFMA() do { \
  __builtin_amdgcn_s_setprio(0); \
  __builtin_amdgcn_s_barrier(); \
  __builtin_amdgcn_sched_barrier(0); \
} while(0)

// ---------------- fp32 -> bf16 cast ----------------
__global__ void k_f2b(const float* __restrict__ in, unsigned short* __restrict__ out, int n4) {
  int i = blockIdx.x * 256 + threadIdx.x;
  if (i >= n4) return;
  float4 v = reinterpret_cast<const float4*>(in)[i];
  ushort4 o;
  o.x = f2bf(v.x); o.y = f2bf(v.y); o.z = f2bf(v.z); o.w = f2bf(v.w);
  reinterpret_cast<ushort4*>(out)[i] = o;
}

// ---------------- RoPE table (fp64 on device; matches np ref closely) ----------------
__global__ void k_rope_tab(float* __restrict__ tab) {
  int t = blockIdx.x, i = threadIdx.x;  // 2048 x 64
  double inv = exp2(-(double)i * (13.287712379549449062 / 64.0)); // 10000^(-i/64)
  double ang = (double)t * inv;
  tab[(t*64 + i)*2 + 0] = (float)cos(ang);
  tab[(t*64 + i)*2 + 1] = (float)sin(ang);
}

// ================= 256x256 8-wave kk-split GEMM core (unchanged, round 4) =================
__device__ __forceinline__ void gemm256_core(
    const unsigned short* __restrict__ Ag,
    const unsigned short* __restrict__ Bg,
    int m0, int n0, short* lds, f32x4 (&acc)[8][4])
{
  const int tid = threadIdx.x;
  const int wid = tid >> 6, lane = tid & 63;
  const int wm = wid >> 2, wn = wid & 3;
  const int r15 = lane & 15, hi4 = lane >> 4;
  const int srow = wid*8 + (lane >> 3);
  const int schunk = (lane & 7) ^ (lane >> 3);

  const f32x4 fz = {0.f, 0.f, 0.f, 0.f};
#pragma unroll
  for (int i = 0; i < 8; i++)
#pragma unroll
    for (int j = 0; j < 4; j++) acc[i][j] = fz;

  int aoff0[8];
#pragma unroll
  for (int mi = 0; mi < 8; mi++) {
    int row = wm*128 + mi*16 + r15;
    aoff0[mi] = row*64 + ((hi4 ^ (row & 7))*8);
  }
  int boff0[4];
#pragma unroll
  for (int ni = 0; ni < 4; ni++) {
    int row = wn*64 + ni*16 + r15;
    boff0[ni] = row*64 + ((hi4 ^ (row & 7))*8);
  }

#define STAGE(G, L, GROW0, KT) do { \
    gl_lds16((G) + (size_t)((GROW0) + srow)*KD + (KT) + schunk*8, (L) + wid*512); \
    gl_lds16((G) + (size_t)((GROW0) + 64 + srow)*KD + (KT) + schunk*8, (L) + 4096 + wid*512); \
  } while(0)

  STAGE(Ag, lds,                        m0,       0);
  STAGE(Ag, lds + 8192,                 m0 + 128, 0);
  STAGE(Bg, lds + 32768,                n0,       0);
  STAGE(Bg, lds + 32768 + 8192,         n0 + 128, 0);
  STAGE(Bg, lds + 32768 + 16384,        n0,       64);
  STAGE(Bg, lds + 32768 + 16384 + 8192, n0 + 128, 64);
  asm volatile("s_waitcnt vmcnt(4)" ::: "memory");
  __builtin_amdgcn_s_barrier();
  __builtin_amdgcn_sched_barrier(0);

#pragma unroll 1
  for (int t = 0; t < NT; t++) {
    const int db = t & 1;
    short* Ab = lds + db*16384;
    short* Bb = lds + 32768 + db*16384;
    short* An = lds + (db ^ 1)*16384;
    const int kt = t*64;
    const bool stA = (t < NT - 1);
    const bool stB = (t < NT - 2);

    bf16x8 a[8], b[4][2];
    // ---- phase 0: kk=0 ----
#pragma unroll
    for (int mi = 0; mi < 8; mi++)
      a[mi] = *reinterpret_cast<const bf16x8*>(Ab + aoff0[mi]);
#pragma unroll
    for (int ni = 0; ni < 4; ni++) {
      b[ni][0] = *reinterpret_cast<const bf16x8*>(Bb + boff0[ni]);
      b[ni][1] = *reinterpret_cast<const bf16x8*>(Bb + (boff0[ni] ^ 32));
    }
    if (stA) {
      STAGE(Ag, An,        m0,       kt + 64);
      STAGE(Ag, An + 8192, m0 + 128, kt + 64);
    }
    PRE_MFMA();
#pragma unroll
    for (int mi = 0; mi < 8; mi++)
#pragma unroll
      for (int ni = 0; ni < 4; ni++)
        acc[mi][ni] = MFMA16(a[mi], b[ni][0], acc[mi][ni]);
    POST_MFMA();

    // ---- phase 1: kk=1 ----
#pragma unroll
    for (int mi = 0; mi < 8; mi++)
      a[mi] = *reinterpret_cast<const bf16x8*>(Ab + (aoff0[mi] ^ 32));
    if (stB) {
      STAGE(Bg, Bb,        n0,       kt + 128);
      STAGE(Bg, Bb + 8192, n0 + 128, kt + 128);
    }
    if (t >= NT - 2) asm volatile("s_waitcnt vmcnt(0)" ::: "memory");
    else             asm volatile("s_waitcnt vmcnt(4)" ::: "memory");
    PRE_MFMA();
#pragma unroll
    for (int mi = 0; mi < 8; mi++)
#pragma unroll
      for (int ni = 0; ni < 4; ni++)
        acc[mi][ni] = MFMA16(a[mi], b[ni][1], acc[mi][ni]);
    POST_MFMA();
  }
#undef STAGE
}

// ---------------- QKV projection + scatter (q,k -> [B,H,T,D]; v -> [B,H,D,T]) ----------------
__global__ __launch_bounds__(512, 2) void k_qkv(
    const unsigned short* __restrict__ xb,
    const unsigned short* __restrict__ wab,
    unsigned short* __restrict__ qr,
    unsigned short* __restrict__ kr,
    unsigned short* __restrict__ vt)
{
  __shared__ __align__(16) short lds[65536];
  f32x4 acc[8][4];
  int bid = blockIdx.x;                      // 768 blocks = 32 mt x 24 nt
  int swz = (bid & 7)*96 + (bid >> 3);       // bijective XCD swizzle (768 % 8 == 0)
  int m0 = (swz / 24)*256, n0 = (swz % 24)*256;
  gemm256_core(xb, wab, m0, n0, lds, acc);

  int tid = threadIdx.x, wid = tid >> 6, lane = tid & 63;
  int wm = wid >> 2, wn = wid & 3, r15 = lane & 15, hi4 = lane >> 4;
  int nw0 = n0 + wn*64;
  int which = nw0 >> 11;            // 0=q, 1=k, 2=v
  int h = (nw0 & 2047) >> 7;        // head (wave's 64 cols lie in one head)
#pragma unroll
  for (int mi = 0; mi < 8; mi++) {
    int m_base = m0 + wm*128 + mi*16 + hi4*4;
    int b = m_base >> 11;
    int t0 = m_base & (TT - 1);
#pragma unroll
    for (int ni = 0; ni < 4; ni++) {
      int d = (nw0 & 127) + ni*16 + r15;
      if (which == 2) {
        ushort4 pv;
        pv.x = f2bf(acc[mi][ni][0]); pv.y = f2bf(acc[mi][ni][1]);
        pv.z = f2bf(acc[mi][ni][2]); pv.w = f2bf(acc[mi][ni][3]);
        *reinterpret_cast<ushort4*>(vt + ((size_t)((b*NHEAD + h)*HD + d))*TT + t0) = pv;
      } else {
        unsigned short* dst = (which == 0) ? qr : kr;
        size_t base = ((size_t)(b*NHEAD + h)*TT + t0)*HD + d;
#pragma unroll
        for (int r = 0; r < 4; r++) dst[base + (size_t)r*HD] = f2bf(acc[mi][ni][r]);
      }
    }
  }
}

// ---------------- output projection ----------------
__global__ __launch_bounds__(512, 2) void k_proj(
    const unsigned short* __restrict__ yb,
    const unsigned short* __restrict__ wpb,
    float* __restrict__ out)
{
  __shared__ __align__(16) short lds[65536];
  f32x4 acc[8][4];
  int bid = blockIdx.x;                      // 256 blocks = 32 mt x 8 nt
  int swz = (bid & 7)*32 + (bid >> 3);
  int m0 = (swz / 8)*256, n0 = (swz % 8)*256;
  gemm256_core(yb, wpb, m0, n0, lds, acc);

  int tid = threadIdx.x, wid = tid >> 6, lane = tid & 63;
  int wm = wid >> 2, wn = wid & 3, r15 = lane & 15, hi4 = lane >> 4;
  int nw0 = n0 + wn*64;
#pragma unroll
  for (int mi = 0; mi < 8; mi++) {
    int m = m0 + wm*128 + mi*16 + hi4*4;
#pragma unroll
    for (int ni = 0; ni < 4; ni++) {
      int n = nw0 + ni*16 + r15;
#pragma unroll
      for (int r = 0; r < 4; r++)
        out[(size_t)(m + r)*CC + n] = acc[mi][ni][r];
    }
  }
}

// ---------------- in-place RoPE on q,k ----------------
__global__ void k_rope_apply(unsigned int* __restrict__ q32, unsigned int* __restrict__ k32,
                             const float* __restrict__ tab) {
  int i = blockIdx.x * 256 + threadIdx.x;   // over B*H*T*64
  int ii = i & 63;
  int t = (i >> 6) & (TT - 1);
  float c = tab[(t*64 + ii)*2], s = tab[(t*64 + ii)*2 + 1];
  unsigned qv = q32[i];
  float q1 = bf2f((unsigned short)qv), q2 = bf2f((unsigned short)(qv >> 16));
  unsigned short lo = f2bf(q1*c - q2*s), hi = f2bf(q1*s + q2*c);
  q32[i] = (unsigned)lo | ((unsigned)hi << 16);
  unsigned kv = k32[i];
  float k1 = bf2f((unsigned short)kv), k2 = bf2f((unsigned short)(kv >> 16));
  lo = f2bf(k1*c - k2*s); hi = f2bf(k1*s + k2*c);
  k32[i] = (unsigned)lo | ((unsigned)hi << 16);
}

// ---------------- causal flash attention (round-5 structure + VALU cuts) ----------------
// grid: 1024 blocks = 64 (b*h) * 16 q-tile PAIRS (pr, 31-pr) -> uniform 33 KV tiles/block
// 256 thr = 4 waves x 16 q-rows; 40KB LDS + ~110 VGPR -> 4 blocks/CU (the proven config).
// Adds vs round 5: (a) wave-uniform full-tile fast path skipping causal mask VALU,
// (b) T13 defer-max (skip O-rescale when max growth <= 8), (c) T5 setprio on MFMA.
__global__ __launch_bounds__(256) void k_attn(
    const unsigned short* __restrict__ qr,
    const unsigned short* __restrict__ kr,
    const unsigned short* __restrict__ vt,
    unsigned short* __restrict__ yb)
{
  __shared__ short Ks[64*128];   // [kv][d], XOR-swizzled
  __shared__ short Vs[128*64];   // [d][kv], XOR-swizzled
  __shared__ short Pw[4*16*64];  // per-wave P, XOR-swizzled
  int bid = blockIdx.x;
  int bh = bid & 63, pr = bid >> 6;
  int tid = threadIdx.x, w = tid >> 6, lane = tid & 63;
  int r15 = lane & 15, hi4 = lane >> 4;
  const unsigned short* qg = qr + (size_t)bh*TT*HD;
  const unsigned short* kg = kr + (size_t)bh*TT*HD;
  const unsigned short* vg = vt + (size_t)bh*HD*TT;
  const f32x4 fz = {0.f,0.f,0.f,0.f};
  const float scale = 0.08838834764831845f; // 1/sqrt(128)
  int b = bh >> 4, h = bh & 15;

#pragma unroll 1
  for (int ph = 0; ph < 2; ph++) {
    int qb = ph ? (31 - pr) : pr;
    int qlo = qb*64 + w*16;
    bf16x8 qf[4];
    {
      int qrow = qlo + r15;
#pragma unroll
      for (int kk = 0; kk < 4; kk++)
        qf[kk] = *reinterpret_cast<const bf16x8*>(qg + (size_t)qrow*HD + kk*32 + hi4*8);
    }
    f32x4 ao[8];
#pragma unroll
    for (int i = 0; i < 8; i++) ao[i] = fz;
    float mrow[4], lsum[4];
#pragma unroll
    for (int r = 0; r < 4; r++) { mrow[r] = -3.0e38f; lsum[r] = 0.f; }
    int ntiles = qb + 1;
    for (int it = 0; it < ntiles; ++it) {
      int kv0 = it*64;
      bool full = (kv0 + 63 <= qlo);   // wave-uniform: tile strictly below diagonal
      __syncthreads();
#pragma unroll
      for (int i = 0; i < 4; i++) {
        int chunk = tid + i*256;
        int row = chunk >> 4, c16 = chunk & 15;
        uint4 v = *reinterpret_cast<const uint4*>(kg + (size_t)(kv0 + row)*HD + c16*8);
        *reinterpret_cast<uint4*>((char*)Ks + row*256 + ((c16 ^ (row & 7))*16)) = v;
      }
#pragma unroll
      for (int i = 0; i < 4; i++) {
        int chunk = tid + i*256;
        int d = chunk >> 3, c8 = chunk & 7;
        uint4 v = *reinterpret_cast<const uint4*>(vg + (size_t)d*TT + kv0 + c8*8);
        *reinterpret_cast<uint4*>((char*)Vs + d*128 + ((c8 ^ (d & 7))*16)) = v;
      }
      __syncthreads();
      f32x4 sacc[4];
      __builtin_amdgcn_s_setprio(1);
#pragma unroll
      for (int n = 0; n < 4; n++) {
        sacc[n] = fz;
#pragma unroll
        for (int kk = 0; kk < 4; kk++) {
          int kvr = n*16 + r15;
          int ch = (kk*4 + hi4) ^ (kvr & 7);
          bf16x8 kf = *reinterpret_cast<const bf16x8*>((char*)Ks + kvr*256 + ch*16);
          sacc[n] = MFMA16(qf[kk], kf, sacc[n]);
        }
      }
      __builtin_amdgcn_s_setprio(0);
      float p[4][4], rmax[4];
#pragma unroll
      for (int r = 0; r < 4; r++) {
        float mx = -3.0e38f;
#pragma unroll
        for (int n = 0; n < 4; n++) {
          float sv = sacc[n][r]*scale;
          if (!full) {
            int kvg = kv0 + n*16 + r15;
            int qgi = qlo + hi4*4 + r;
            sv = (kvg <= qgi) ? sv : -3.0e38f;
          }
          p[n][r] = sv;
          mx = fmaxf(mx, sv);
        }
        rmax[r] = mx;
      }
#pragma unroll
      for (int mm = 1; mm < 16; mm <<= 1)
#pragma unroll
        for (int r = 0; r < 4; r++) rmax[r] = fmaxf(rmax[r], __shfl_xor(rmax[r], mm));
      // T13 defer-max: skip rescale when max growth bounded
      bool ng = (rmax[0] <= mrow[0] + 8.f) && (rmax[1] <= mrow[1] + 8.f)
             && (rmax[2] <= mrow[2] + 8.f) && (rmax[3] <= mrow[3] + 8.f);
      bool defer = __all(ng);
      float alpha[4];
#pragma unroll
      for (int r = 0; r < 4; r++) {
        if (defer) { alpha[r] = 1.f; }
        else {
          float mnew = fmaxf(mrow[r], rmax[r]);
          alpha[r] = __expf(mrow[r] - mnew);
          mrow[r] = mnew;
        }
      }
      float rsum[4];
#pragma unroll
      for (int r = 0; r < 4; r++) {
        float sum = 0.f;
#pragma unroll
        for (int n = 0; n < 4; n++) {
          float pv = __expf(p[n][r] - mrow[r]);
          p[n][r] = pv; sum += pv;
        }
        rsum[r] = sum;
      }
#pragma unroll
      for (int mm = 1; mm < 16; mm <<= 1)
#pragma unroll
        for (int r = 0; r < 4; r++) rsum[r] += __shfl_xor(rsum[r], mm);
#pragma unroll
      for (int r = 0; r < 4; r++) lsum[r] = lsum[r]*alpha[r] + rsum[r];
      if (!defer) {
#pragma unroll
        for (int i = 0; i < 8; i++)
#pragma unroll
          for (int r = 0; r < 4; r++) ao[i][r] *= alpha[r];
      }
#pragma unroll
      for (int r = 0; r < 4; r++) {
        int prow = hi4*4 + r;
#pragma unroll
        for (int n = 0; n < 4; n++) {
          int col = n*16 + r15;
          Pw[w*1024 + prow*64 + (col ^ ((prow & 7) << 3))] = (short)f2bf(p[n][r]);
        }
      }
      __builtin_amdgcn_s_setprio(1);
#pragma unroll
      for (int kk = 0; kk < 2; kk++) {
        int prow = r15;
        int ch = (kk*4 + hi4) ^ (prow & 7);
        bf16x8 pa = *reinterpret_cast<const bf16x8*>((char*)(Pw + w*1024) + prow*128 + ch*16);
#pragma unroll
        for (int ds_ = 0; ds_ < 8; ds_++) {
          int d = ds_*16 + r15;
          int vch = (kk*4 + hi4) ^ (d & 7);
          bf16x8 vf = *reinterpret_cast<const bf16x8*>((char*)Vs + d*128 + vch*16);
          ao[ds_] = MFMA16(pa, vf, ao[ds_]);
        }
      }
      __builtin_amdgcn_s_setprio(0);
    }
#pragma unroll
    for (int r = 0; r < 4; r++) {
      int t = qlo + hi4*4 + r;
      float inv = 1.f / lsum[r];
      size_t base = ((size_t)b*TT + t)*CC + h*HD + r15;
#pragma unroll
      for (int ds_ = 0; ds_ < 8; ds_++)
        yb[base + ds_*16] = f2bf(ao[ds_][r] * inv);
    }
  }
}

extern "C" void kernel_launch(void* const* d_in, const int* in_sizes, int n_in,
                              void* d_out, int out_size, void* d_ws, size_t ws_size,
                              hipStream_t stream) {
  const float* x  = (const float*)d_in[0];
  const float* wa = (const float*)d_in[1];
  const float* wp = (const float*)d_in[2];
  float* out = (float*)d_out;
  char* ws = (char*)d_ws;
  size_t off = 0;
  unsigned short* xb  = (unsigned short*)(ws + off); off += (size_t)MTOT*CC*2;
  unsigned short* wab = (unsigned short*)(ws + off); off += (size_t)3*CC*CC*2;
  unsigned short* wpb = (unsigned short*)(ws + off); off += (size_t)CC*CC*2;
  unsigned short* qr  = (unsigned short*)(ws + off); off += (size_t)MTOT*CC*2;
  unsigned short* kr  = (unsigned short*)(ws + off); off += (size_t)MTOT*CC*2;
  unsigned short* vt  = (unsigned short*)(ws + off); off += (size_t)MTOT*CC*2;
  unsigned short* yb  = (unsigned short*)(ws + off); off += (size_t)MTOT*CC*2;
  float* tab          = (float*)(ws + off);          off += (size_t)TT*64*2*4;

  k_f2b<<<dim3(16384), dim3(256), 0, stream>>>(x,  xb,  MTOT*CC/4);
  k_f2b<<<dim3(12288), dim3(256), 0, stream>>>(wa, wab, 3*CC*CC/4);
  k_f2b<<<dim3(4096),  dim3(256), 0, stream>>>(wp, wpb, CC*CC/4);
  k_rope_tab<<<dim3(TT), dim3(64), 0, stream>>>(tab);
  k_qkv<<<dim3(768), dim3(512), 0, stream>>>(xb, wab, qr, kr, vt);
  k_rope_apply<<<dim3(32768), dim3(256), 0, stream>>>((unsigned int*)qr, (unsigned int*)kr, tab);
  k_attn<<<dim3(1024), dim3(256), 0, stream>>>(qr, kr, vt, yb);
  k_proj<<<dim3(256), dim3(512), 0, stream>>>(yb, wpb, out);
}

// Round 12
// 485.466 us; speedup vs baseline: 1.1754x; 1.0187x over previous
//
#include <hip/hip_runtime.h>
#include <stdint.h>

#define TT 2048      // T
#define CC 2048      // C
#define NHEAD 16
#define HD 128
#define NB 4         // batch
#define MTOT (NB*TT) // 8192
#define KD 2048      // GEMM K (both projections)
#define NT 32        // K tiles of 64

typedef __attribute__((ext_vector_type(8))) short bf16x8;
typedef __attribute__((ext_vector_type(4))) float f32x4;
typedef __attribute__((ext_vector_type(16))) float f32x16;
typedef __attribute__((ext_vector_type(4))) unsigned u32x4;

__device__ __forceinline__ unsigned short f2bf(float f) {
  unsigned u = __float_as_uint(f);
  u += 0x7FFF + ((u >> 16) & 1);
  return (unsigned short)(u >> 16);
}
__device__ __forceinline__ float bf2f(unsigned short h) {
  return __uint_as_float(((unsigned)h) << 16);
}

__device__ __forceinline__ void gl_lds16(const unsigned short* g, short* l) {
  __builtin_amdgcn_global_load_lds(
      (const __attribute__((address_space(1))) void*)(g),
      (__attribute__((address_space(3))) void*)(l), 16, 0, 0);
}

#define MFMA16(a, b, c) __builtin_amdgcn_mfma_f32_16x16x32_bf16((a), (b), (c), 0, 0, 0)
#define MFMA32(a, b, c) __builtin_amdgcn_mfma_f32_32x32x16_bf16((a), (b), (c), 0, 0, 0)

#define PRE_MFMA() do { \
  __builtin_amdgcn_s_barrier(); \
  asm volatile("s_waitcnt lgkmcnt(0)" ::: "memory"); \
  __builtin_amdgcn_s_setprio(1); \
} while(0)
#define POST_MFMA() do { \
  __builtin_amdgcn_s_setprio(0); \
  __builtin_amdgcn_s_barrier(); \
  __builtin_amdgcn_sched_barrier(0); \
} while(0)

// ---------------- fp32 -> bf16 cast ----------------
__global__ void k_f2b(const float* __restrict__ in, unsigned short* __restrict__ out, int n4) {
  int i = blockIdx.x * 256 + threadIdx.x;
  if (i >= n4) return;
  float4 v = reinterpret_cast<const float4*>(in)[i];
  ushort4 o;
  o.x = f2bf(v.x); o.y = f2bf(v.y); o.z = f2bf(v.z); o.w = f2bf(v.w);
  reinterpret_cast<ushort4*>(out)[i] = o;
}

// ---------------- RoPE table ----------------
__global__ void k_rope_tab(float* __restrict__ tab) {
  int t = blockIdx.x, i = threadIdx.x;  // 2048 x 64
  double inv = exp2(-(double)i * (13.287712379549449062 / 64.0)); // 10000^(-i/64)
  double ang = (double)t * inv;
  tab[(t*64 + i)*2 + 0] = (float)cos(ang);
  tab[(t*64 + i)*2 + 1] = (float)sin(ang);
}

// ================= 256x256 8-wave kk-split GEMM core (unchanged, round 4) =================
__device__ __forceinline__ void gemm256_core(
    const unsigned short* __restrict__ Ag,
    const unsigned short* __restrict__ Bg,
    int m0, int n0, short* lds, f32x4 (&acc)[8][4])
{
  const int tid = threadIdx.x;
  const int wid = tid >> 6, lane = tid & 63;
  const int wm = wid >> 2, wn = wid & 3;
  const int r15 = lane & 15, hi4 = lane >> 4;
  const int srow = wid*8 + (lane >> 3);
  const int schunk = (lane & 7) ^ (lane >> 3);

  const f32x4 fz = {0.f, 0.f, 0.f, 0.f};
#pragma unroll
  for (int i = 0; i < 8; i++)
#pragma unroll
    for (int j = 0; j < 4; j++) acc[i][j] = fz;

  int aoff0[8];
#pragma unroll
  for (int mi = 0; mi < 8; mi++) {
    int row = wm*128 + mi*16 + r15;
    aoff0[mi] = row*64 + ((hi4 ^ (row & 7))*8);
  }
  int boff0[4];
#pragma unroll
  for (int ni = 0; ni < 4; ni++) {
    int row = wn*64 + ni*16 + r15;
    boff0[ni] = row*64 + ((hi4 ^ (row & 7))*8);
  }

#define STAGE(G, L, GROW0, KT) do { \
    gl_lds16((G) + (size_t)((GROW0) + srow)*KD + (KT) + schunk*8, (L) + wid*512); \
    gl_lds16((G) + (size_t)((GROW0) + 64 + srow)*KD + (KT) + schunk*8, (L) + 4096 + wid*512); \
  } while(0)

  STAGE(Ag, lds,                        m0,       0);
  STAGE(Ag, lds + 8192,                 m0 + 128, 0);
  STAGE(Bg, lds + 32768,                n0,       0);
  STAGE(Bg, lds + 32768 + 8192,         n0 + 128, 0);
  STAGE(Bg, lds + 32768 + 16384,        n0,       64);
  STAGE(Bg, lds + 32768 + 16384 + 8192, n0 + 128, 64);
  asm volatile("s_waitcnt vmcnt(4)" ::: "memory");
  __builtin_amdgcn_s_barrier();
  __builtin_amdgcn_sched_barrier(0);

#pragma unroll 1
  for (int t = 0; t < NT; t++) {
    const int db = t & 1;
    short* Ab = lds + db*16384;
    short* Bb = lds + 32768 + db*16384;
    short* An = lds + (db ^ 1)*16384;
    const int kt = t*64;
    const bool stA = (t < NT - 1);
    const bool stB = (t < NT - 2);

    bf16x8 a[8], b[4][2];
#pragma unroll
    for (int mi = 0; mi < 8; mi++)
      a[mi] = *reinterpret_cast<const bf16x8*>(Ab + aoff0[mi]);
#pragma unroll
    for (int ni = 0; ni < 4; ni++) {
      b[ni][0] = *reinterpret_cast<const bf16x8*>(Bb + boff0[ni]);
      b[ni][1] = *reinterpret_cast<const bf16x8*>(Bb + (boff0[ni] ^ 32));
    }
    if (stA) {
      STAGE(Ag, An,        m0,       kt + 64);
      STAGE(Ag, An + 8192, m0 + 128, kt + 64);
    }
    PRE_MFMA();
#pragma unroll
    for (int mi = 0; mi < 8; mi++)
#pragma unroll
      for (int ni = 0; ni < 4; ni++)
        acc[mi][ni] = MFMA16(a[mi], b[ni][0], acc[mi][ni]);
    POST_MFMA();

#pragma unroll
    for (int mi = 0; mi < 8; mi++)
      a[mi] = *reinterpret_cast<const bf16x8*>(Ab + (aoff0[mi] ^ 32));
    if (stB) {
      STAGE(Bg, Bb,        n0,       kt + 128);
      STAGE(Bg, Bb + 8192, n0 + 128, kt + 128);
    }
    if (t >= NT - 2) asm volatile("s_waitcnt vmcnt(0)" ::: "memory");
    else             asm volatile("s_waitcnt vmcnt(4)" ::: "memory");
    PRE_MFMA();
#pragma unroll
    for (int mi = 0; mi < 8; mi++)
#pragma unroll
      for (int ni = 0; ni < 4; ni++)
        acc[mi][ni] = MFMA16(a[mi], b[ni][1], acc[mi][ni]);
    POST_MFMA();
  }
#undef STAGE
}

// ---------------- QKV projection + scatter ----------------
__global__ __launch_bounds__(512, 2) void k_qkv(
    const unsigned short* __restrict__ xb,
    const unsigned short* __restrict__ wab,
    unsigned short* __restrict__ qr,
    unsigned short* __restrict__ kr,
    unsigned short* __restrict__ vt)
{
  __shared__ __align__(16) short lds[65536];
  f32x4 acc[8][4];
  int bid = blockIdx.x;                      // 768 blocks
  int swz = (bid & 7)*96 + (bid >> 3);
  int m0 = (swz / 24)*256, n0 = (swz % 24)*256;
  gemm256_core(xb, wab, m0, n0, lds, acc);

  int tid = threadIdx.x, wid = tid >> 6, lane = tid & 63;
  int wm = wid >> 2, wn = wid & 3, r15 = lane & 15, hi4 = lane >> 4;
  int nw0 = n0 + wn*64;
  int which = nw0 >> 11;
  int h = (nw0 & 2047) >> 7;
#pragma unroll
  for (int mi = 0; mi < 8; mi++) {
    int m_base = m0 + wm*128 + mi*16 + hi4*4;
    int b = m_base >> 11;
    int t0 = m_base & (TT - 1);
#pragma unroll
    for (int ni = 0; ni < 4; ni++) {
      int d = (nw0 & 127) + ni*16 + r15;
      if (which == 2) {
        ushort4 pv;
        pv.x = f2bf(acc[mi][ni][0]); pv.y = f2bf(acc[mi][ni][1]);
        pv.z = f2bf(acc[mi][ni][2]); pv.w = f2bf(acc[mi][ni][3]);
        *reinterpret_cast<ushort4*>(vt + ((size_t)((b*NHEAD + h)*HD + d))*TT + t0) = pv;
      } else {
        unsigned short* dst = (which == 0) ? qr : kr;
        size_t base = ((size_t)(b*NHEAD + h)*TT + t0)*HD + d;
#pragma unroll
        for (int r = 0; r < 4; r++) dst[base + (size_t)r*HD] = f2bf(acc[mi][ni][r]);
      }
    }
  }
}

// ---------------- output projection ----------------
__global__ __launch_bounds__(512, 2) void k_proj(
    const unsigned short* __restrict__ yb,
    const unsigned short* __restrict__ wpb,
    float* __restrict__ out)
{
  __shared__ __align__(16) short lds[65536];
  f32x4 acc[8][4];
  int bid = blockIdx.x;                      // 256 blocks
  int swz = (bid & 7)*32 + (bid >> 3);
  int m0 = (swz / 8)*256, n0 = (swz % 8)*256;
  gemm256_core(yb, wpb, m0, n0, lds, acc);

  int tid = threadIdx.x, wid = tid >> 6, lane = tid & 63;
  int wm = wid >> 2, wn = wid & 3, r15 = lane & 15, hi4 = lane >> 4;
  int nw0 = n0 + wn*64;
#pragma unroll
  for (int mi = 0; mi < 8; mi++) {
    int m = m0 + wm*128 + mi*16 + hi4*4;
#pragma unroll
    for (int ni = 0; ni < 4; ni++) {
      int n = nw0 + ni*16 + r15;
#pragma unroll
      for (int r = 0; r < 4; r++)
        out[(size_t)(m + r)*CC + n] = acc[mi][ni][r];
    }
  }
}

// ---------------- in-place RoPE on q,k ----------------
__global__ void k_rope_apply(unsigned int* __restrict__ q32, unsigned int* __restrict__ k32,
                             const float* __restrict__ tab) {
  int i = blockIdx.x * 256 + threadIdx.x;
  int ii = i & 63;
  int t = (i >> 6) & (TT - 1);
  float c = tab[(t*64 + ii)*2], s = tab[(t*64 + ii)*2 + 1];
  unsigned qv = q32[i];
  float q1 = bf2f((unsigned short)qv), q2 = bf2f((unsigned short)(qv >> 16));
  unsigned short lo = f2bf(q1*c - q2*s), hi = f2bf(q1*s + q2*c);
  q32[i] = (unsigned)lo | ((unsigned)hi << 16);
  unsigned kv = k32[i];
  float k1 = bf2f((unsigned short)kv), k2 = bf2f((unsigned short)(kv >> 16));
  lo = f2bf(k1*c - k2*s); hi = f2bf(k1*s + k2*c);
  k32[i] = (unsigned)lo | ((unsigned)hi << 16);
}

// ---------------- causal flash attention: swapped-QK^T 32x32, in-register softmax ----------------
// grid: 512 blocks = 64 bh x 8 PAIRS (pr, 15-pr) of 128-row q-blocks -> uniform 34 tiles.
// 256 thr = 4 waves x 32 q-rows (q = lane&31). KVBLK=64. LDS 64.5KB -> 2 blocks/CU.
// Swapped QK^T: S^T = mfma32(A=K, B=Q) -> lane holds 32 of its q-row's 64 scores
//   (partner lane^32 holds the rest; kvl = (r&3)+8*(r>>2)+4*hi per C/D formula m74/m101).
// Softmax fully in-register: in-lane trees + __shfl_xor(·,32) partner combine
//   (direction-unambiguous; round-11's permlane asm direction was the failure).
// P -> PV A-frags via 16 v_cvt_pk_bf16_f32 + shfl_xor/select (T12 variant). No P LDS.
// PV: mfma32(pa, Vt-frag), V staged d-major. T13 defer-max. Double-buffered K/V via
// global_load_lds (inverse-swizzled source, rule 21), issue-early (round-7 flow).
__global__ __launch_bounds__(256, 1) void k_attn(
    const unsigned short* __restrict__ qr,
    const unsigned short* __restrict__ kr,
    const unsigned short* __restrict__ vt,
    unsigned short* __restrict__ yb)
{
  __shared__ __align__(16) short Ks[2][64*128];   // [buf][kv][d], chunk-XOR swizzled
  __shared__ __align__(16) short Vs[2][128*64];   // [buf][d][kv], chunk-XOR swizzled
  __shared__ float alds[4][32];                   // per-wave alpha/linv broadcast
  int bid = blockIdx.x;
  int bh = bid & 63, pr = bid >> 6;               // pr 0..7
  int tid = threadIdx.x, w = tid >> 6, lane = tid & 63;
  int l31 = lane & 31, hi = lane >> 5;
  const unsigned short* qg = qr + (size_t)bh*TT*HD;
  const unsigned short* kg = kr + (size_t)bh*TT*HD;
  const unsigned short* vg = vt + (size_t)bh*HD*TT;
  const float scale = 0.08838834764831845f; // 1/sqrt(128)
  int b = bh >> 4, h = bh & 15;

  // inverse-swizzled per-lane global source offsets (elements) — round-8 proven
  int ksoff[4], vsoff[4];
#pragma unroll
  for (int i = 0; i < 4; i++) {
    int rK = (w*4 + i)*4 + (lane >> 4);
    int cK = (lane & 15) ^ (rK & 7);
    ksoff[i] = rK*HD + cK*8;
    int dV = (w*4 + i)*8 + (lane >> 3);
    int cV = (lane & 7) ^ (dV & 7);
    vsoff[i] = dV*TT + cV*8;
  }

#define STAGE_KV(BUF, KV0) do { \
    _Pragma("unroll") \
    for (int i_ = 0; i_ < 4; i_++) { \
      gl_lds16(kg + (size_t)(KV0)*HD + ksoff[i_], &Ks[BUF][(w*4 + i_)*512]); \
      gl_lds16(vg + (KV0) + vsoff[i_],            &Vs[BUF][(w*4 + i_)*512]); \
    } \
  } while(0)

#pragma unroll 1
  for (int ph = 0; ph < 2; ph++) {
    int qb = ph ? (15 - pr) : pr;
    int qlo = qb*128 + w*32;         // wave's first q row
    int qgi = qlo + l31;             // this lane's q row (global)
    // Q fragments (B-operand): col=q=lane&31, k-chunk selected by hi
    bf16x8 qf[8];
#pragma unroll
    for (int kk = 0; kk < 8; kk++)
      qf[kk] = *reinterpret_cast<const bf16x8*>(qg + (size_t)qgi*HD + kk*16 + hi*8);

    f32x16 ao[4];
#pragma unroll
    for (int dt = 0; dt < 4; dt++)
#pragma unroll
      for (int r = 0; r < 16; r++) ao[dt][r] = 0.f;
    float mrow = -3.0e38f, lsum = 0.f;
    int ntiles = 2*qb + 2;

    STAGE_KV(0, 0);
    __syncthreads();
    int cur = 0;

#pragma unroll 1
    for (int it = 0; it < ntiles; ++it) {
      int kv0 = it*64;
      if (it + 1 < ntiles) STAGE_KV(cur ^ 1, kv0 + 64);
      if (kv0 <= qlo + 31) {         // wave-uniform: skip fully-masked tiles
        const short* Kc = Ks[cur];
        const short* Vc = Vs[cur];
        bool full = (kv0 + 63 <= qlo);
        // ---- swapped QK^T: S^T = mfma(K, Q) ----
        f32x16 s0, s1;
#pragma unroll
        for (int r = 0; r < 16; r++) { s0[r] = 0.f; s1[r] = 0.f; }
        __builtin_amdgcn_s_setprio(1);
#pragma unroll
        for (int kk = 0; kk < 8; kk++) {
          int row0 = l31, row1 = 32 + l31;
          int ch0 = ((2*kk + hi) ^ (row0 & 7));
          int ch1 = ((2*kk + hi) ^ (row1 & 7));
          bf16x8 kf0 = *reinterpret_cast<const bf16x8*>((const char*)Kc + row0*256 + ch0*16);
          bf16x8 kf1 = *reinterpret_cast<const bf16x8*>((const char*)Kc + row1*256 + ch1*16);
          s0 = MFMA32(kf0, qf[kk], s0);
          s1 = MFMA32(kf1, qf[kk], s1);
        }
        __builtin_amdgcn_s_setprio(0);
        // ---- scale + mask; p[r] = S[q=l31][kv0 + kvl], p[16+r] = +32 ----
        float p[32];
#pragma unroll
        for (int r = 0; r < 16; r++) {
          int kvl = (r & 3) + 8*(r >> 2) + 4*hi;
          float v0 = s0[r]*scale, v1 = s1[r]*scale;
          if (!full) {
            v0 = (kv0 + kvl      <= qgi) ? v0 : -3.0e38f;
            v1 = (kv0 + 32 + kvl <= qgi) ? v1 : -3.0e38f;
          }
          p[r] = v0; p[16 + r] = v1;
        }
        // ---- row max: in-lane tree + partner combine (shfl_xor 32) ----
        float t16[16];
#pragma unroll
        for (int i = 0; i < 16; i++) t16[i] = fmaxf(p[i], p[i + 16]);
#pragma unroll
        for (int i = 0; i < 8; i++) t16[i] = fmaxf(t16[i], t16[i + 8]);
#pragma unroll
        for (int i = 0; i < 4; i++) t16[i] = fmaxf(t16[i], t16[i + 4]);
        float mx = fmaxf(fmaxf(t16[0], t16[1]), fmaxf(t16[2], t16[3]));
        mx = fmaxf(mx, __shfl_xor(mx, 32));
        // ---- T13 defer-max ----
        bool defer = __all(mx <= mrow + 8.f);
        if (!defer) {
          float mnew = fmaxf(mrow, mx);
          float alpha = __expf(mrow - mnew);
          mrow = mnew;
          lsum *= alpha;
          if (lane < 32) alds[w][lane] = alpha;
#pragma unroll
          for (int r = 0; r < 16; r++) {
            int ql = (r & 3) + 8*(r >> 2) + 4*hi;
            float av = alds[w][ql];
#pragma unroll
            for (int dt = 0; dt < 4; dt++) ao[dt][r] *= av;
          }
        }
        // ---- exp + row sum ----
#pragma unroll
        for (int i = 0; i < 32; i++) p[i] = __expf(p[i] - mrow);
#pragma unroll
        for (int i = 0; i < 16; i++) t16[i] = p[i] + p[i + 16];
#pragma unroll
        for (int i = 0; i < 8; i++) t16[i] = t16[i] + t16[i + 8];
#pragma unroll
        for (int i = 0; i < 4; i++) t16[i] = t16[i] + t16[i + 4];
        float rs = (t16[0] + t16[1]) + (t16[2] + t16[3]);
        rs += __shfl_xor(rs, 32);
        lsum += rs;
        // ---- T12 (direction-agnostic): P -> A-frags via cvt_pk + shfl_xor + select ----
        // hi0 lane needs k-words {own(p0,1),(p2,3), partner(p0,1),(p2,3)} = kv 8ks..8ks+7
        // hi1 lane needs {partner(p4,5),(p6,7), own(p4,5),(p6,7)}          = kv 8ks+8..15
        bf16x8 pa[4];
#pragma unroll
        for (int ks = 0; ks < 4; ks++) {
          const int base = (ks >> 1)*16 + (ks & 1)*8;
          unsigned a0, a1, b0, b1;
          asm("v_cvt_pk_bf16_f32 %0, %1, %2" : "=v"(a0) : "v"(p[base + 0]), "v"(p[base + 1]));
          asm("v_cvt_pk_bf16_f32 %0, %1, %2" : "=v"(a1) : "v"(p[base + 2]), "v"(p[base + 3]));
          asm("v_cvt_pk_bf16_f32 %0, %1, %2" : "=v"(b0) : "v"(p[base + 4]), "v"(p[base + 5]));
          asm("v_cvt_pk_bf16_f32 %0, %1, %2" : "=v"(b1) : "v"(p[base + 6]), "v"(p[base + 7]));
          unsigned sa0 = (unsigned)__shfl_xor((int)a0, 32);
          unsigned sa1 = (unsigned)__shfl_xor((int)a1, 32);
          unsigned sb0 = (unsigned)__shfl_xor((int)b0, 32);
          unsigned sb1 = (unsigned)__shfl_xor((int)b1, 32);
          u32x4 pw;
          pw.x = hi ? sb0 : a0;
          pw.y = hi ? sb1 : a1;
          pw.z = hi ? b0 : sa0;
          pw.w = hi ? b1 : sa1;
          pa[ks] = __builtin_bit_cast(bf16x8, pw);
        }
        // ---- PV: O[q][d] += P[q][kv] V[kv][d]  (B-frag = Vt[d][kv], contiguous) ----
        __builtin_amdgcn_s_setprio(1);
#pragma unroll
        for (int dt = 0; dt < 4; dt++) {
          int d = dt*32 + l31;
#pragma unroll
          for (int ks = 0; ks < 4; ks++) {
            int ch = ((2*ks + hi) ^ (d & 7));
            bf16x8 vf = *reinterpret_cast<const bf16x8*>((const char*)Vc + d*128 + ch*16);
            ao[dt] = MFMA32(pa[ks], vf, ao[dt]);
          }
        }
        __builtin_amdgcn_s_setprio(0);
      }
      __syncthreads();   // drains vmcnt -> next buffer published; readers done
      cur ^= 1;
    }
    // ---- epilogue: broadcast 1/lsum per q, write O ----
    if (lane < 32) alds[w][lane] = 1.0f / lsum;
#pragma unroll
    for (int r = 0; r < 16; r++) {
      int ql = (r & 3) + 8*(r >> 2) + 4*hi;
      float lv = alds[w][ql];
      int t = qlo + ql;
      size_t base = ((size_t)b*TT + t)*CC + h*HD + l31;
#pragma unroll
      for (int dt = 0; dt < 4; dt++)
        yb[base + dt*32] = f2bf(ao[dt][r] * lv);
    }
    __syncthreads();     // alds reused next phase; keep waves aligned
  }
#undef STAGE_KV
}

extern "C" void kernel_launch(void* const* d_in, const int* in_sizes, int n_in,
                              void* d_out, int out_size, void* d_ws, size_t ws_size,
                              hipStream_t stream) {
  const float* x  = (const float*)d_in[0];
  const float* wa = (const float*)d_in[1];
  const float* wp = (const float*)d_in[2];
  float* out = (float*)d_out;
  char* ws = (char*)d_ws;
  size_t off = 0;
  unsigned short* xb  = (unsigned short*)(ws + off); off += (size_t)MTOT*CC*2;
  unsigned short* wab = (unsigned short*)(ws + off); off += (size_t)3*CC*CC*2;
  unsigned short* wpb = (unsigned short*)(ws + off); off += (size_t)CC*CC*2;
  unsigned short* qr  = (unsigned short*)(ws + off); off += (size_t)MTOT*CC*2;
  unsigned short* kr  = (unsigned short*)(ws + off); off += (size_t)MTOT*CC*2;
  unsigned short* vt  = (unsigned short*)(ws + off); off += (size_t)MTOT*CC*2;
  unsigned short* yb  = (unsigned short*)(ws + off); off += (size_t)MTOT*CC*2;
  float* tab          = (float*)(ws + off);          off += (size_t)TT*64*2*4;

  k_f2b<<<dim3(16384), dim3(256), 0, stream>>>(x,  xb,  MTOT*CC/4);
  k_f2b<<<dim3(12288), dim3(256), 0, stream>>>(wa, wab, 3*CC*CC/4);
  k_f2b<<<dim3(4096),  dim3(256), 0, stream>>>(wp, wpb, CC*CC/4);
  k_rope_tab<<<dim3(TT), dim3(64), 0, stream>>>(tab);
  k_qkv<<<dim3(768), dim3(512), 0, stream>>>(xb, wab, qr, kr, vt);
  k_rope_apply<<<dim3(32768), dim3(256), 0, stream>>>((unsigned int*)qr, (unsigned int*)kr, tab);
  k_attn<<<dim3(512), dim3(256), 0, stream>>>(qr, kr, vt, yb);
  k_proj<<<dim3(256), dim3(512), 0, stream>>>(yb, wpb, out);
}

// Round 13
// 470.870 us; speedup vs baseline: 1.2118x; 1.0310x over previous
//
#include <hip/hip_runtime.h>
#include <stdint.h>

#define TT 2048      // T
#define CC 2048      // C
#define NHEAD 16
#define HD 128
#define NB 4         // batch
#define MTOT (NB*TT) // 8192
#define KD 2048      // GEMM K (both projections)
#define NT 32        // K tiles of 64

typedef __attribute__((ext_vector_type(8))) short bf16x8;
typedef __attribute__((ext_vector_type(4))) float f32x4;
typedef __attribute__((ext_vector_type(16))) float f32x16;
typedef __attribute__((ext_vector_type(4))) unsigned u32x4;

__device__ __forceinline__ unsigned short f2bf(float f) {
  unsigned u = __float_as_uint(f);
  u += 0x7FFF + ((u >> 16) & 1);
  return (unsigned short)(u >> 16);
}
__device__ __forceinline__ float bf2f(unsigned short h) {
  return __uint_as_float(((unsigned)h) << 16);
}

__device__ __forceinline__ void gl_lds16(const unsigned short* g, short* l) {
  __builtin_amdgcn_global_load_lds(
      (const __attribute__((address_space(1))) void*)(g),
      (__attribute__((address_space(3))) void*)(l), 16, 0, 0);
}

#define MFMA16(a, b, c) __builtin_amdgcn_mfma_f32_16x16x32_bf16((a), (b), (c), 0, 0, 0)
#define MFMA32(a, b, c) __builtin_amdgcn_mfma_f32_32x32x16_bf16((a), (b), (c), 0, 0, 0)

// ---------------- fp32 -> bf16 cast ----------------
__global__ void k_f2b(const float* __restrict__ in, unsigned short* __restrict__ out, int n4) {
  int i = blockIdx.x * 256 + threadIdx.x;
  if (i >= n4) return;
  float4 v = reinterpret_cast<const float4*>(in)[i];
  ushort4 o;
  o.x = f2bf(v.x); o.y = f2bf(v.y); o.z = f2bf(v.z); o.w = f2bf(v.w);
  reinterpret_cast<ushort4*>(out)[i] = o;
}

// ---------------- RoPE table ----------------
__global__ void k_rope_tab(float* __restrict__ tab) {
  int t = blockIdx.x, i = threadIdx.x;  // 2048 x 64
  double inv = exp2(-(double)i * (13.287712379549449062 / 64.0)); // 10000^(-i/64)
  double ang = (double)t * inv;
  tab[(t*64 + i)*2 + 0] = (float)cos(ang);
  tab[(t*64 + i)*2 + 1] = (float)sin(ang);
}

// ================= 256x256 8-wave merged-cluster GEMM core =================
// C[m][n] = sum_k A[m][k]*B[n][k]; A:[M][2048], B:[N][2048] row-major bf16 bits.
// 512 thr = 8 waves (2M x 4N); per-wave 128x64 out; acc[8][4]; chunk-XOR swizzle.
// Per K-tile: ONE read+MFMA interval (24 ds_read issued up front, 64 MFMA cluster;
// compiler emits counted lgkmcnt so LDS drain overlaps matrix work — m97 mechanism),
// then lgkm0+barrier#1 (B(t) reads drained block-wide) -> stage B(t+2) into live
// B buffer is safe; vmcnt(4) completes B(t+1)+A(t+1), leaves B(t+2) flying (T4,
// counted, never 0 mid-loop); barrier#2 publishes tile t+1. 2 barriers/K-tile.
// Hazard ledger: A(t+1)->An other-buffer always safe; prologue leaves B(1) in
// flight past its barrier; tail drains vmcnt(0) for last two tiles.
__device__ __forceinline__ void gemm256_core(
    const unsigned short* __restrict__ Ag,
    const unsigned short* __restrict__ Bg,
    int m0, int n0, short* lds, f32x4 (&acc)[8][4])
{
  const int tid = threadIdx.x;
  const int wid = tid >> 6, lane = tid & 63;
  const int wm = wid >> 2, wn = wid & 3;
  const int r15 = lane & 15, hi4 = lane >> 4;
  const int srow = wid*8 + (lane >> 3);
  const int schunk = (lane & 7) ^ (lane >> 3);

  const f32x4 fz = {0.f, 0.f, 0.f, 0.f};
#pragma unroll
  for (int i = 0; i < 8; i++)
#pragma unroll
    for (int j = 0; j < 4; j++) acc[i][j] = fz;

  int aoff0[8];
#pragma unroll
  for (int mi = 0; mi < 8; mi++) {
    int row = wm*128 + mi*16 + r15;
    aoff0[mi] = row*64 + ((hi4 ^ (row & 7))*8);
  }
  int boff0[4];
#pragma unroll
  for (int ni = 0; ni < 4; ni++) {
    int row = wn*64 + ni*16 + r15;
    boff0[ni] = row*64 + ((hi4 ^ (row & 7))*8);
  }

#define STAGE(G, L, GROW0, KT) do { \
    gl_lds16((G) + (size_t)((GROW0) + srow)*KD + (KT) + schunk*8, (L) + wid*512); \
    gl_lds16((G) + (size_t)((GROW0) + 64 + srow)*KD + (KT) + schunk*8, (L) + 4096 + wid*512); \
  } while(0)

  // prologue: A(0), B(0) [complete], B(1) [stays in flight]
  STAGE(Ag, lds,                        m0,       0);
  STAGE(Ag, lds + 8192,                 m0 + 128, 0);
  STAGE(Bg, lds + 32768,                n0,       0);
  STAGE(Bg, lds + 32768 + 8192,         n0 + 128, 0);
  STAGE(Bg, lds + 32768 + 16384,        n0,       64);
  STAGE(Bg, lds + 32768 + 16384 + 8192, n0 + 128, 64);
  asm volatile("s_waitcnt vmcnt(4)" ::: "memory");
  __builtin_amdgcn_s_barrier();
  __builtin_amdgcn_sched_barrier(0);

#pragma unroll 1
  for (int t = 0; t < NT; t++) {
    const int db = t & 1;
    short* Ab = lds + db*16384;
    short* Bb = lds + 32768 + db*16384;
    short* An = lds + (db ^ 1)*16384;
    const int kt = t*64;

    bf16x8 a[8][2], b[4][2];
#pragma unroll
    for (int mi = 0; mi < 8; mi++) {
      a[mi][0] = *reinterpret_cast<const bf16x8*>(Ab + aoff0[mi]);
      a[mi][1] = *reinterpret_cast<const bf16x8*>(Ab + (aoff0[mi] ^ 32));
    }
#pragma unroll
    for (int ni = 0; ni < 4; ni++) {
      b[ni][0] = *reinterpret_cast<const bf16x8*>(Bb + boff0[ni]);
      b[ni][1] = *reinterpret_cast<const bf16x8*>(Bb + (boff0[ni] ^ 32));
    }
    if (t < NT - 1) {
      STAGE(Ag, An,        m0,       kt + 64);
      STAGE(Ag, An + 8192, m0 + 128, kt + 64);
    }
    __builtin_amdgcn_s_setprio(1);
#pragma unroll
    for (int kk = 0; kk < 2; kk++)
#pragma unroll
      for (int mi = 0; mi < 8; mi++)
#pragma unroll
        for (int ni = 0; ni < 4; ni++)
          acc[mi][ni] = MFMA16(a[mi][kk], b[ni][kk], acc[mi][ni]);
    __builtin_amdgcn_s_setprio(0);
    asm volatile("s_waitcnt lgkmcnt(0)" ::: "memory");
    __builtin_amdgcn_s_barrier();      // #1: all waves' tile-t reads complete
    __builtin_amdgcn_sched_barrier(0);
    if (t < NT - 2) {
      STAGE(Bg, Bb,        n0,       kt + 128);
      STAGE(Bg, Bb + 8192, n0 + 128, kt + 128);
    }
    if (t >= NT - 2) asm volatile("s_waitcnt vmcnt(0)" ::: "memory");
    else             asm volatile("s_waitcnt vmcnt(4)" ::: "memory");
    __builtin_amdgcn_s_barrier();      // #2: tile t+1 published
    __builtin_amdgcn_sched_barrier(0);
  }
#undef STAGE
}

// ---------------- QKV projection + scatter + fused RoPE ----------------
// q,k get RoPE applied in fp32 BEFORE bf16 rounding (pair element via shfl_xor(v,1):
// d's bit0 == lane's bit0, so partner column d^1 lives in lane^1 of same wave).
__global__ __launch_bounds__(512, 2) void k_qkv(
    const unsigned short* __restrict__ xb,
    const unsigned short* __restrict__ wab,
    const float* __restrict__ tab,
    unsigned short* __restrict__ qr,
    unsigned short* __restrict__ kr,
    unsigned short* __restrict__ vt)
{
  __shared__ __align__(16) short lds[65536];
  f32x4 acc[8][4];
  int bid = blockIdx.x;                      // 768 blocks
  int swz = (bid & 7)*96 + (bid >> 3);       // bijective XCD swizzle
  int m0 = (swz / 24)*256, n0 = (swz % 24)*256;
  gemm256_core(xb, wab, m0, n0, lds, acc);

  int tid = threadIdx.x, wid = tid >> 6, lane = tid & 63;
  int wm = wid >> 2, wn = wid & 3, r15 = lane & 15, hi4 = lane >> 4;
  int nw0 = n0 + wn*64;
  int which = nw0 >> 11;            // 0=q, 1=k, 2=v
  int h = (nw0 & 2047) >> 7;
#pragma unroll
  for (int mi = 0; mi < 8; mi++) {
    int m_base = m0 + wm*128 + mi*16 + hi4*4;
    int b = m_base >> 11;
    int t0 = m_base & (TT - 1);
#pragma unroll
    for (int ni = 0; ni < 4; ni++) {
      int d = (nw0 & 127) + ni*16 + r15;
      if (which == 2) {
        ushort4 pv;
        pv.x = f2bf(acc[mi][ni][0]); pv.y = f2bf(acc[mi][ni][1]);
        pv.z = f2bf(acc[mi][ni][2]); pv.w = f2bf(acc[mi][ni][3]);
        *reinterpret_cast<ushort4*>(vt + ((size_t)((b*NHEAD + h)*HD + d))*TT + t0) = pv;
      } else {
        unsigned short* dst = (which == 0) ? qr : kr;
        size_t base = ((size_t)(b*NHEAD + h)*TT + t0)*HD + d;
        int j = d >> 1;
        bool odd = (d & 1);
#pragma unroll
        for (int r = 0; r < 4; r++) {
          float v = acc[mi][ni][r];
          float pv = __shfl_xor(v, 1);
          float2 cs = *reinterpret_cast<const float2*>(tab + ((size_t)(t0 + r)*64 + j)*2);
          float res = odd ? (pv*cs.y + v*cs.x) : (v*cs.x - pv*cs.y);
          dst[base + (size_t)r*HD] = f2bf(res);
        }
      }
    }
  }
}

// ---------------- output projection ----------------
__global__ __launch_bounds__(512, 2) void k_proj(
    const unsigned short* __restrict__ yb,
    const unsigned short* __restrict__ wpb,
    float* __restrict__ out)
{
  __shared__ __align__(16) short lds[65536];
  f32x4 acc[8][4];
  int bid = blockIdx.x;                      // 256 blocks
  int swz = (bid & 7)*32 + (bid >> 3);
  int m0 = (swz / 8)*256, n0 = (swz % 8)*256;
  gemm256_core(yb, wpb, m0, n0, lds, acc);

  int tid = threadIdx.x, wid = tid >> 6, lane = tid & 63;
  int wm = wid >> 2, wn = wid & 3, r15 = lane & 15, hi4 = lane >> 4;
  int nw0 = n0 + wn*64;
#pragma unroll
  for (int mi = 0; mi < 8; mi++) {
    int m = m0 + wm*128 + mi*16 + hi4*4;
#pragma unroll
    for (int ni = 0; ni < 4; ni++) {
      int n = nw0 + ni*16 + r15;
#pragma unroll
      for (int r = 0; r < 4; r++)
        out[(size_t)(m + r)*CC + n] = acc[mi][ni][r];
    }
  }
}

// ---------------- causal flash attention: swapped-QK^T 32x32, in-register softmax ----------------
// (unchanged from round 12 — passed at absmax 0.015625)
__global__ __launch_bounds__(256, 1) void k_attn(
    const unsigned short* __restrict__ qr,
    const unsigned short* __restrict__ kr,
    const unsigned short* __restrict__ vt,
    unsigned short* __restrict__ yb)
{
  __shared__ __align__(16) short Ks[2][64*128];   // [buf][kv][d], chunk-XOR swizzled
  __shared__ __align__(16) short Vs[2][128*64];   // [buf][d][kv], chunk-XOR swizzled
  __shared__ float alds[4][32];                   // per-wave alpha/linv broadcast
  int bid = blockIdx.x;
  int bh = bid & 63, pr = bid >> 6;               // pr 0..7
  int tid = threadIdx.x, w = tid >> 6, lane = tid & 63;
  int l31 = lane & 31, hi = lane >> 5;
  const unsigned short* qg = qr + (size_t)bh*TT*HD;
  const unsigned short* kg = kr + (size_t)bh*TT*HD;
  const unsigned short* vg = vt + (size_t)bh*HD*TT;
  const float scale = 0.08838834764831845f; // 1/sqrt(128)
  int b = bh >> 4, h = bh & 15;

  int ksoff[4], vsoff[4];
#pragma unroll
  for (int i = 0; i < 4; i++) {
    int rK = (w*4 + i)*4 + (lane >> 4);
    int cK = (lane & 15) ^ (rK & 7);
    ksoff[i] = rK*HD + cK*8;
    int dV = (w*4 + i)*8 + (lane >> 3);
    int cV = (lane & 7) ^ (dV & 7);
    vsoff[i] = dV*TT + cV*8;
  }

#define STAGE_KV(BUF, KV0) do { \
    _Pragma("unroll") \
    for (int i_ = 0; i_ < 4; i_++) { \
      gl_lds16(kg + (size_t)(KV0)*HD + ksoff[i_], &Ks[BUF][(w*4 + i_)*512]); \
      gl_lds16(vg + (KV0) + vsoff[i_],            &Vs[BUF][(w*4 + i_)*512]); \
    } \
  } while(0)

#pragma unroll 1
  for (int ph = 0; ph < 2; ph++) {
    int qb = ph ? (15 - pr) : pr;
    int qlo = qb*128 + w*32;
    int qgi = qlo + l31;
    bf16x8 qf[8];
#pragma unroll
    for (int kk = 0; kk < 8; kk++)
      qf[kk] = *reinterpret_cast<const bf16x8*>(qg + (size_t)qgi*HD + kk*16 + hi*8);

    f32x16 ao[4];
#pragma unroll
    for (int dt = 0; dt < 4; dt++)
#pragma unroll
      for (int r = 0; r < 16; r++) ao[dt][r] = 0.f;
    float mrow = -3.0e38f, lsum = 0.f;
    int ntiles = 2*qb + 2;

    STAGE_KV(0, 0);
    __syncthreads();
    int cur = 0;

#pragma unroll 1
    for (int it = 0; it < ntiles; ++it) {
      int kv0 = it*64;
      if (it + 1 < ntiles) STAGE_KV(cur ^ 1, kv0 + 64);
      if (kv0 <= qlo + 31) {
        const short* Kc = Ks[cur];
        const short* Vc = Vs[cur];
        bool full = (kv0 + 63 <= qlo);
        f32x16 s0, s1;
#pragma unroll
        for (int r = 0; r < 16; r++) { s0[r] = 0.f; s1[r] = 0.f; }
        __builtin_amdgcn_s_setprio(1);
#pragma unroll
        for (int kk = 0; kk < 8; kk++) {
          int row0 = l31, row1 = 32 + l31;
          int ch0 = ((2*kk + hi) ^ (row0 & 7));
          int ch1 = ((2*kk + hi) ^ (row1 & 7));
          bf16x8 kf0 = *reinterpret_cast<const bf16x8*>((const char*)Kc + row0*256 + ch0*16);
          bf16x8 kf1 = *reinterpret_cast<const bf16x8*>((const char*)Kc + row1*256 + ch1*16);
          s0 = MFMA32(kf0, qf[kk], s0);
          s1 = MFMA32(kf1, qf[kk], s1);
        }
        __builtin_amdgcn_s_setprio(0);
        float p[32];
#pragma unroll
        for (int r = 0; r < 16; r++) {
          int kvl = (r & 3) + 8*(r >> 2) + 4*hi;
          float v0 = s0[r]*scale, v1 = s1[r]*scale;
          if (!full) {
            v0 = (kv0 + kvl      <= qgi) ? v0 : -3.0e38f;
            v1 = (kv0 + 32 + kvl <= qgi) ? v1 : -3.0e38f;
          }
          p[r] = v0; p[16 + r] = v1;
        }
        float t16[16];
#pragma unroll
        for (int i = 0; i < 16; i++) t16[i] = fmaxf(p[i], p[i + 16]);
#pragma unroll
        for (int i = 0; i < 8; i++) t16[i] = fmaxf(t16[i], t16[i + 8]);
#pragma unroll
        for (int i = 0; i < 4; i++) t16[i] = fmaxf(t16[i], t16[i + 4]);
        float mx = fmaxf(fmaxf(t16[0], t16[1]), fmaxf(t16[2], t16[3]));
        mx = fmaxf(mx, __shfl_xor(mx, 32));
        bool defer = __all(mx <= mrow + 8.f);
        if (!defer) {
          float mnew = fmaxf(mrow, mx);
          float alpha = __expf(mrow - mnew);
          mrow = mnew;
          lsum *= alpha;
          if (lane < 32) alds[w][lane] = alpha;
#pragma unroll
          for (int r = 0; r < 16; r++) {
            int ql = (r & 3) + 8*(r >> 2) + 4*hi;
            float av = alds[w][ql];
#pragma unroll
            for (int dt = 0; dt < 4; dt++) ao[dt][r] *= av;
          }
        }
#pragma unroll
        for (int i = 0; i < 32; i++) p[i] = __expf(p[i] - mrow);
#pragma unroll
        for (int i = 0; i < 16; i++) t16[i] = p[i] + p[i + 16];
#pragma unroll
        for (int i = 0; i < 8; i++) t16[i] = t16[i] + t16[i + 8];
#pragma unroll
        for (int i = 0; i < 4; i++) t16[i] = t16[i] + t16[i + 4];
        float rs = (t16[0] + t16[1]) + (t16[2] + t16[3]);
        rs += __shfl_xor(rs, 32);
        lsum += rs;
        bf16x8 pa[4];
#pragma unroll
        for (int ks = 0; ks < 4; ks++) {
          const int base = (ks >> 1)*16 + (ks & 1)*8;
          unsigned a0, a1, b0, b1;
          asm("v_cvt_pk_bf16_f32 %0, %1, %2" : "=v"(a0) : "v"(p[base + 0]), "v"(p[base + 1]));
          asm("v_cvt_pk_bf16_f32 %0, %1, %2" : "=v"(a1) : "v"(p[base + 2]), "v"(p[base + 3]));
          asm("v_cvt_pk_bf16_f32 %0, %1, %2" : "=v"(b0) : "v"(p[base + 4]), "v"(p[base + 5]));
          asm("v_cvt_pk_bf16_f32 %0, %1, %2" : "=v"(b1) : "v"(p[base + 6]), "v"(p[base + 7]));
          unsigned sa0 = (unsigned)__shfl_xor((int)a0, 32);
          unsigned sa1 = (unsigned)__shfl_xor((int)a1, 32);
          unsigned sb0 = (unsigned)__shfl_xor((int)b0, 32);
          unsigned sb1 = (unsigned)__shfl_xor((int)b1, 32);
          u32x4 pw;
          pw.x = hi ? sb0 : a0;
          pw.y = hi ? sb1 : a1;
          pw.z = hi ? b0 : sa0;
          pw.w = hi ? b1 : sa1;
          pa[ks] = __builtin_bit_cast(bf16x8, pw);
        }
        __builtin_amdgcn_s_setprio(1);
#pragma unroll
        for (int dt = 0; dt < 4; dt++) {
          int d = dt*32 + l31;
#pragma unroll
          for (int ks = 0; ks < 4; ks++) {
            int ch = ((2*ks + hi) ^ (d & 7));
            bf16x8 vf = *reinterpret_cast<const bf16x8*>((const char*)Vc + d*128 + ch*16);
            ao[dt] = MFMA32(pa[ks], vf, ao[dt]);
          }
        }
        __builtin_amdgcn_s_setprio(0);
      }
      __syncthreads();
      cur ^= 1;
    }
    if (lane < 32) alds[w][lane] = 1.0f / lsum;
#pragma unroll
    for (int r = 0; r < 16; r++) {
      int ql = (r & 3) + 8*(r >> 2) + 4*hi;
      float lv = alds[w][ql];
      int t = qlo + ql;
      size_t base = ((size_t)b*TT + t)*CC + h*HD + l31;
#pragma unroll
      for (int dt = 0; dt < 4; dt++)
        yb[base + dt*32] = f2bf(ao[dt][r] * lv);
    }
    __syncthreads();
  }
#undef STAGE_KV
}

extern "C" void kernel_launch(void* const* d_in, const int* in_sizes, int n_in,
                              void* d_out, int out_size, void* d_ws, size_t ws_size,
                              hipStream_t stream) {
  const float* x  = (const float*)d_in[0];
  const float* wa = (const float*)d_in[1];
  const float* wp = (const float*)d_in[2];
  float* out = (float*)d_out;
  char* ws = (char*)d_ws;
  size_t off = 0;
  unsigned short* xb  = (unsigned short*)(ws + off); off += (size_t)MTOT*CC*2;
  unsigned short* wab = (unsigned short*)(ws + off); off += (size_t)3*CC*CC*2;
  unsigned short* wpb = (unsigned short*)(ws + off); off += (size_t)CC*CC*2;
  unsigned short* qr  = (unsigned short*)(ws + off); off += (size_t)MTOT*CC*2;
  unsigned short* kr  = (unsigned short*)(ws + off); off += (size_t)MTOT*CC*2;
  unsigned short* vt  = (unsigned short*)(ws + off); off += (size_t)MTOT*CC*2;
  unsigned short* yb  = (unsigned short*)(ws + off); off += (size_t)MTOT*CC*2;
  float* tab          = (float*)(ws + off);          off += (size_t)TT*64*2*4;

  k_f2b<<<dim3(16384), dim3(256), 0, stream>>>(x,  xb,  MTOT*CC/4);
  k_f2b<<<dim3(12288), dim3(256), 0, stream>>>(wa, wab, 3*CC*CC/4);
  k_f2b<<<dim3(4096),  dim3(256), 0, stream>>>(wp, wpb, CC*CC/4);
  k_rope_tab<<<dim3(TT), dim3(64), 0, stream>>>(tab);
  k_qkv<<<dim3(768), dim3(512), 0, stream>>>(xb, wab, tab, qr, kr, vt);
  k_attn<<<dim3(512), dim3(256), 0, stream>>>(qr, kr, vt, yb);
  k_proj<<<dim3(256), dim3(512), 0, stream>>>(yb, wpb, out);
}

// Round 14
// 410.952 us; speedup vs baseline: 1.3885x; 1.1458x over previous
//
#include <hip/hip_runtime.h>
#include <stdint.h>

#define TT 2048      // T
#define CC 2048      // C
#define NHEAD 16
#define HD 128
#define NB 4         // batch
#define MTOT (NB*TT) // 8192
#define KD 2048      // GEMM K (both projections)
#define NT 32        // K tiles of 64

typedef __attribute__((ext_vector_type(8))) short bf16x8;
typedef __attribute__((ext_vector_type(4))) float f32x4;
typedef __attribute__((ext_vector_type(16))) float f32x16;
typedef __attribute__((ext_vector_type(4))) unsigned u32x4;

__device__ __forceinline__ unsigned short f2bf(float f) {
  unsigned u = __float_as_uint(f);
  u += 0x7FFF + ((u >> 16) & 1);
  return (unsigned short)(u >> 16);
}
__device__ __forceinline__ float bf2f(unsigned short h) {
  return __uint_as_float(((unsigned)h) << 16);
}

__device__ __forceinline__ void gl_lds16(const unsigned short* g, short* l) {
  __builtin_amdgcn_global_load_lds(
      (const __attribute__((address_space(1))) void*)(g),
      (__attribute__((address_space(3))) void*)(l), 16, 0, 0);
}

#define MFMA16(a, b, c) __builtin_amdgcn_mfma_f32_16x16x32_bf16((a), (b), (c), 0, 0, 0)
#define MFMA32(a, b, c) __builtin_amdgcn_mfma_f32_32x32x16_bf16((a), (b), (c), 0, 0, 0)

#define PRE_MFMA() do { \
  __builtin_amdgcn_s_barrier(); \
  asm volatile("s_waitcnt lgkmcnt(0)" ::: "memory"); \
  __builtin_amdgcn_s_setprio(1); \
} while(0)
#define POST_MFMA() do { \
  __builtin_amdgcn_s_setprio(0); \
  __builtin_amdgcn_s_barrier(); \
  __builtin_amdgcn_sched_barrier(0); \
} while(0)

// ---------------- fp32 -> bf16 cast ----------------
__global__ void k_f2b(const float* __restrict__ in, unsigned short* __restrict__ out, int n4) {
  int i = blockIdx.x * 256 + threadIdx.x;
  if (i >= n4) return;
  float4 v = reinterpret_cast<const float4*>(in)[i];
  ushort4 o;
  o.x = f2bf(v.x); o.y = f2bf(v.y); o.z = f2bf(v.z); o.w = f2bf(v.w);
  reinterpret_cast<ushort4*>(out)[i] = o;
}

// ---------------- RoPE table ----------------
__global__ void k_rope_tab(float* __restrict__ tab) {
  int t = blockIdx.x, i = threadIdx.x;  // 2048 x 64
  double inv = exp2(-(double)i * (13.287712379549449062 / 64.0)); // 10000^(-i/64)
  double ang = (double)t * inv;
  tab[(t*64 + i)*2 + 0] = (float)cos(ang);
  tab[(t*64 + i)*2 + 1] = (float)sin(ang);
}

// ================= 256x256 8-wave kk-split GEMM core (round-4 proven, 945 TF) =================
__device__ __forceinline__ void gemm256_core(
    const unsigned short* __restrict__ Ag,
    const unsigned short* __restrict__ Bg,
    int m0, int n0, short* lds, f32x4 (&acc)[8][4])
{
  const int tid = threadIdx.x;
  const int wid = tid >> 6, lane = tid & 63;
  const int wm = wid >> 2, wn = wid & 3;
  const int r15 = lane & 15, hi4 = lane >> 4;
  const int srow = wid*8 + (lane >> 3);
  const int schunk = (lane & 7) ^ (lane >> 3);

  const f32x4 fz = {0.f, 0.f, 0.f, 0.f};
#pragma unroll
  for (int i = 0; i < 8; i++)
#pragma unroll
    for (int j = 0; j < 4; j++) acc[i][j] = fz;

  int aoff0[8];
#pragma unroll
  for (int mi = 0; mi < 8; mi++) {
    int row = wm*128 + mi*16 + r15;
    aoff0[mi] = row*64 + ((hi4 ^ (row & 7))*8);
  }
  int boff0[4];
#pragma unroll
  for (int ni = 0; ni < 4; ni++) {
    int row = wn*64 + ni*16 + r15;
    boff0[ni] = row*64 + ((hi4 ^ (row & 7))*8);
  }

#define STAGE(G, L, GROW0, KT) do { \
    gl_lds16((G) + (size_t)((GROW0) + srow)*KD + (KT) + schunk*8, (L) + wid*512); \
    gl_lds16((G) + (size_t)((GROW0) + 64 + srow)*KD + (KT) + schunk*8, (L) + 4096 + wid*512); \
  } while(0)

  // prologue: A(0), B(0) [complete], then B(1) [stays in flight]
  STAGE(Ag, lds,                        m0,       0);
  STAGE(Ag, lds + 8192,                 m0 + 128, 0);
  STAGE(Bg, lds + 32768,                n0,       0);
  STAGE(Bg, lds + 32768 + 8192,         n0 + 128, 0);
  STAGE(Bg, lds + 32768 + 16384,        n0,       64);
  STAGE(Bg, lds + 32768 + 16384 + 8192, n0 + 128, 64);
  asm volatile("s_waitcnt vmcnt(4)" ::: "memory");
  __builtin_amdgcn_s_barrier();
  __builtin_amdgcn_sched_barrier(0);

#pragma unroll 1
  for (int t = 0; t < NT; t++) {
    const int db = t & 1;
    short* Ab = lds + db*16384;
    short* Bb = lds + 32768 + db*16384;
    short* An = lds + (db ^ 1)*16384;
    const int kt = t*64;
    const bool stA = (t < NT - 1);
    const bool stB = (t < NT - 2);

    bf16x8 a[8], b[4][2];
    // ---- phase 0: kk=0 ----
#pragma unroll
    for (int mi = 0; mi < 8; mi++)
      a[mi] = *reinterpret_cast<const bf16x8*>(Ab + aoff0[mi]);
#pragma unroll
    for (int ni = 0; ni < 4; ni++) {
      b[ni][0] = *reinterpret_cast<const bf16x8*>(Bb + boff0[ni]);
      b[ni][1] = *reinterpret_cast<const bf16x8*>(Bb + (boff0[ni] ^ 32));
    }
    if (stA) {
      STAGE(Ag, An,        m0,       kt + 64);
      STAGE(Ag, An + 8192, m0 + 128, kt + 64);
    }
    PRE_MFMA();
#pragma unroll
    for (int mi = 0; mi < 8; mi++)
#pragma unroll
      for (int ni = 0; ni < 4; ni++)
        acc[mi][ni] = MFMA16(a[mi], b[ni][0], acc[mi][ni]);
    POST_MFMA();

    // ---- phase 1: kk=1 ----
#pragma unroll
    for (int mi = 0; mi < 8; mi++)
      a[mi] = *reinterpret_cast<const bf16x8*>(Ab + (aoff0[mi] ^ 32));
    if (stB) {
      STAGE(Bg, Bb,        n0,       kt + 128);
      STAGE(Bg, Bb + 8192, n0 + 128, kt + 128);
    }
    if (t >= NT - 2) asm volatile("s_waitcnt vmcnt(0)" ::: "memory");
    else             asm volatile("s_waitcnt vmcnt(4)" ::: "memory");
    PRE_MFMA();
#pragma unroll
    for (int mi = 0; mi < 8; mi++)
#pragma unroll
      for (int ni = 0; ni < 4; ni++)
        acc[mi][ni] = MFMA16(a[mi], b[ni][1], acc[mi][ni]);
    POST_MFMA();
  }
#undef STAGE
}

// ---------------- QKV projection + scatter + fused RoPE ----------------
// q,k get RoPE applied in fp32 BEFORE bf16 rounding (pair element via shfl_xor(v,1):
// d's bit0 == lane's bit0, so partner column d^1 lives in lane^1 of same wave).
__global__ __launch_bounds__(512, 2) void k_qkv(
    const unsigned short* __restrict__ xb,
    const unsigned short* __restrict__ wab,
    const float* __restrict__ tab,
    unsigned short* __restrict__ qr,
    unsigned short* __restrict__ kr,
    unsigned short* __restrict__ vt)
{
  __shared__ __align__(16) short lds[65536];
  f32x4 acc[8][4];
  int bid = blockIdx.x;                      // 768 blocks
  int swz = (bid & 7)*96 + (bid >> 3);       // bijective XCD swizzle
  int m0 = (swz / 24)*256, n0 = (swz % 24)*256;
  gemm256_core(xb, wab, m0, n0, lds, acc);

  int tid = threadIdx.x, wid = tid >> 6, lane = tid & 63;
  int wm = wid >> 2, wn = wid & 3, r15 = lane & 15, hi4 = lane >> 4;
  int nw0 = n0 + wn*64;
  int which = nw0 >> 11;            // 0=q, 1=k, 2=v
  int h = (nw0 & 2047) >> 7;
#pragma unroll
  for (int mi = 0; mi < 8; mi++) {
    int m_base = m0 + wm*128 + mi*16 + hi4*4;
    int b = m_base >> 11;
    int t0 = m_base & (TT - 1);
#pragma unroll
    for (int ni = 0; ni < 4; ni++) {
      int d = (nw0 & 127) + ni*16 + r15;
      if (which == 2) {
        ushort4 pv;
        pv.x = f2bf(acc[mi][ni][0]); pv.y = f2bf(acc[mi][ni][1]);
        pv.z = f2bf(acc[mi][ni][2]); pv.w = f2bf(acc[mi][ni][3]);
        *reinterpret_cast<ushort4*>(vt + ((size_t)((b*NHEAD + h)*HD + d))*TT + t0) = pv;
      } else {
        unsigned short* dst = (which == 0) ? qr : kr;
        size_t base = ((size_t)(b*NHEAD + h)*TT + t0)*HD + d;
        int j = d >> 1;
        bool odd = (d & 1);
#pragma unroll
        for (int r = 0; r < 4; r++) {
          float v = acc[mi][ni][r];
          float pv = __shfl_xor(v, 1);
          float2 cs = *reinterpret_cast<const float2*>(tab + ((size_t)(t0 + r)*64 + j)*2);
          float res = odd ? (pv*cs.y + v*cs.x) : (v*cs.x - pv*cs.y);
          dst[base + (size_t)r*HD] = f2bf(res);
        }
      }
    }
  }
}

// ---------------- output projection ----------------
__global__ __launch_bounds__(512, 2) void k_proj(
    const unsigned short* __restrict__ yb,
    const unsigned short* __restrict__ wpb,
    float* __restrict__ out)
{
  __shared__ __align__(16) short lds[65536];
  f32x4 acc[8][4];
  int bid = blockIdx.x;                      // 256 blocks
  int swz = (bid & 7)*32 + (bid >> 3);
  int m0 = (swz / 8)*256, n0 = (swz % 8)*256;
  gemm256_core(yb, wpb, m0, n0, lds, acc);

  int tid = threadIdx.x, wid = tid >> 6, lane = tid & 63;
  int wm = wid >> 2, wn = wid & 3, r15 = lane & 15, hi4 = lane >> 4;
  int nw0 = n0 + wn*64;
#pragma unroll
  for (int mi = 0; mi < 8; mi++) {
    int m = m0 + wm*128 + mi*16 + hi4*4;
#pragma unroll
    for (int ni = 0; ni < 4; ni++) {
      int n = nw0 + ni*16 + r15;
#pragma unroll
      for (int r = 0; r < 4; r++)
        out[(size_t)(m + r)*CC + n] = acc[mi][ni][r];
    }
  }
}

// ---------------- causal flash attention: swapped-QK^T 32x32, in-register softmax ----------------
// 8-WAVE blocks (m214 structure): 512 thr = 8 waves x 32 q-rows = 256 q-rows/block.
// grid: 256 blocks = 64 bh x 4 PAIRS (qb, 7-qb) of 256-row q-blocks -> uniform 36
// KV tiles/block, exactly 1 block/CU (tail-free). Each staged K/V tile now serves
// 8 waves (was 4) -> staging traffic + gl_lds issue per MFMA halves.
// Per-wave inner loop identical to round 12 (passed, absmax 0.015625).
__global__ __launch_bounds__(512, 1) void k_attn(
    const unsigned short* __restrict__ qr,
    const unsigned short* __restrict__ kr,
    const unsigned short* __restrict__ vt,
    unsigned short* __restrict__ yb)
{
  __shared__ __align__(16) short Ks[2][64*128];   // [buf][kv][d], chunk-XOR swizzled
  __shared__ __align__(16) short Vs[2][128*64];   // [buf][d][kv], chunk-XOR swizzled
  __shared__ float alds[8][32];                   // per-wave alpha/linv broadcast
  int bid = blockIdx.x;
  int bh = bid & 63, pr = bid >> 6;               // pr 0..3
  int tid = threadIdx.x, w = tid >> 6, lane = tid & 63;
  int l31 = lane & 31, hi = lane >> 5;
  const unsigned short* qg = qr + (size_t)bh*TT*HD;
  const unsigned short* kg = kr + (size_t)bh*TT*HD;
  const unsigned short* vg = vt + (size_t)bh*HD*TT;
  const float scale = 0.08838834764831845f; // 1/sqrt(128)
  int b = bh >> 4, h = bh & 15;

  // inverse-swizzled per-lane global source offsets (elements); 16 chunks/tile,
  // wave w stages chunks {2w, 2w+1} of K and of V.
  int ksoff[2], vsoff[2];
#pragma unroll
  for (int i = 0; i < 2; i++) {
    int c = w*2 + i;
    int rK = c*4 + (lane >> 4);
    int cK = (lane & 15) ^ (rK & 7);
    ksoff[i] = rK*HD + cK*8;
    int dV = c*8 + (lane >> 3);
    int cV = (lane & 7) ^ (dV & 7);
    vsoff[i] = dV*TT + cV*8;
  }

#define STAGE_KV(BUF, KV0) do { \
    _Pragma("unroll") \
    for (int i_ = 0; i_ < 2; i_++) { \
      gl_lds16(kg + (size_t)(KV0)*HD + ksoff[i_], &Ks[BUF][(w*2 + i_)*512]); \
      gl_lds16(vg + (KV0) + vsoff[i_],            &Vs[BUF][(w*2 + i_)*512]); \
    } \
  } while(0)

#pragma unroll 1
  for (int ph = 0; ph < 2; ph++) {
    int qb = ph ? (7 - pr) : pr;
    int qlo = qb*256 + w*32;         // wave's first q row
    int qgi = qlo + l31;             // this lane's q row (global)
    bf16x8 qf[8];
#pragma unroll
    for (int kk = 0; kk < 8; kk++)
      qf[kk] = *reinterpret_cast<const bf16x8*>(qg + (size_t)qgi*HD + kk*16 + hi*8);

    f32x16 ao[4];
#pragma unroll
    for (int dt = 0; dt < 4; dt++)
#pragma unroll
      for (int r = 0; r < 16; r++) ao[dt][r] = 0.f;
    float mrow = -3.0e38f, lsum = 0.f;
    int ntiles = 4*qb + 4;           // even -> buffer parity resets each phase

    STAGE_KV(0, 0);
    __syncthreads();
    int cur = 0;

#pragma unroll 1
    for (int it = 0; it < ntiles; ++it) {
      int kv0 = it*64;
      if (it + 1 < ntiles) STAGE_KV(cur ^ 1, kv0 + 64);
      if (kv0 <= qlo + 31) {         // wave-uniform: skip fully-masked tiles
        const short* Kc = Ks[cur];
        const short* Vc = Vs[cur];
        bool full = (kv0 + 63 <= qlo);
        // ---- swapped QK^T: S^T = mfma(K, Q) ----
        f32x16 s0, s1;
#pragma unroll
        for (int r = 0; r < 16; r++) { s0[r] = 0.f; s1[r] = 0.f; }
        __builtin_amdgcn_s_setprio(1);
#pragma unroll
        for (int kk = 0; kk < 8; kk++) {
          int row0 = l31, row1 = 32 + l31;
          int ch0 = ((2*kk + hi) ^ (row0 & 7));
          int ch1 = ((2*kk + hi) ^ (row1 & 7));
          bf16x8 kf0 = *reinterpret_cast<const bf16x8*>((const char*)Kc + row0*256 + ch0*16);
          bf16x8 kf1 = *reinterpret_cast<const bf16x8*>((const char*)Kc + row1*256 + ch1*16);
          s0 = MFMA32(kf0, qf[kk], s0);
          s1 = MFMA32(kf1, qf[kk], s1);
        }
        __builtin_amdgcn_s_setprio(0);
        // ---- scale + mask ----
        float p[32];
#pragma unroll
        for (int r = 0; r < 16; r++) {
          int kvl = (r & 3) + 8*(r >> 2) + 4*hi;
          float v0 = s0[r]*scale, v1 = s1[r]*scale;
          if (!full) {
            v0 = (kv0 + kvl      <= qgi) ? v0 : -3.0e38f;
            v1 = (kv0 + 32 + kvl <= qgi) ? v1 : -3.0e38f;
          }
          p[r] = v0; p[16 + r] = v1;
        }
        // ---- row max ----
        float t16[16];
#pragma unroll
        for (int i = 0; i < 16; i++) t16[i] = fmaxf(p[i], p[i + 16]);
#pragma unroll
        for (int i = 0; i < 8; i++) t16[i] = fmaxf(t16[i], t16[i + 8]);
#pragma unroll
        for (int i = 0; i < 4; i++) t16[i] = fmaxf(t16[i], t16[i + 4]);
        float mx = fmaxf(fmaxf(t16[0], t16[1]), fmaxf(t16[2], t16[3]));
        mx = fmaxf(mx, __shfl_xor(mx, 32));
        // ---- T13 defer-max ----
        bool defer = __all(mx <= mrow + 8.f);
        if (!defer) {
          float mnew = fmaxf(mrow, mx);
          float alpha = __expf(mrow - mnew);
          mrow = mnew;
          lsum *= alpha;
          if (lane < 32) alds[w][lane] = alpha;
#pragma unroll
          for (int r = 0; r < 16; r++) {
            int ql = (r & 3) + 8*(r >> 2) + 4*hi;
            float av = alds[w][ql];
#pragma unroll
            for (int dt = 0; dt < 4; dt++) ao[dt][r] *= av;
          }
        }
        // ---- exp + row sum ----
#pragma unroll
        for (int i = 0; i < 32; i++) p[i] = __expf(p[i] - mrow);
#pragma unroll
        for (int i = 0; i < 16; i++) t16[i] = p[i] + p[i + 16];
#pragma unroll
        for (int i = 0; i < 8; i++) t16[i] = t16[i] + t16[i + 8];
#pragma unroll
        for (int i = 0; i < 4; i++) t16[i] = t16[i] + t16[i + 4];
        float rs = (t16[0] + t16[1]) + (t16[2] + t16[3]);
        rs += __shfl_xor(rs, 32);
        lsum += rs;
        // ---- T12: P -> A-frags via cvt_pk + shfl_xor + select ----
        bf16x8 pa[4];
#pragma unroll
        for (int ks = 0; ks < 4; ks++) {
          const int base = (ks >> 1)*16 + (ks & 1)*8;
          unsigned a0, a1, b0, b1;
          asm("v_cvt_pk_bf16_f32 %0, %1, %2" : "=v"(a0) : "v"(p[base + 0]), "v"(p[base + 1]));
          asm("v_cvt_pk_bf16_f32 %0, %1, %2" : "=v"(a1) : "v"(p[base + 2]), "v"(p[base + 3]));
          asm("v_cvt_pk_bf16_f32 %0, %1, %2" : "=v"(b0) : "v"(p[base + 4]), "v"(p[base + 5]));
          asm("v_cvt_pk_bf16_f32 %0, %1, %2" : "=v"(b1) : "v"(p[base + 6]), "v"(p[base + 7]));
          unsigned sa0 = (unsigned)__shfl_xor((int)a0, 32);
          unsigned sa1 = (unsigned)__shfl_xor((int)a1, 32);
          unsigned sb0 = (unsigned)__shfl_xor((int)b0, 32);
          unsigned sb1 = (unsigned)__shfl_xor((int)b1, 32);
          u32x4 pw;
          pw.x = hi ? sb0 : a0;
          pw.y = hi ? sb1 : a1;
          pw.z = hi ? b0 : sa0;
          pw.w = hi ? b1 : sa1;
          pa[ks] = __builtin_bit_cast(bf16x8, pw);
        }
        // ---- PV ----
        __builtin_amdgcn_s_setprio(1);
#pragma unroll
        for (int dt = 0; dt < 4; dt++) {
          int d = dt*32 + l31;
#pragma unroll
          for (int ks = 0; ks < 4; ks++) {
            int ch = ((2*ks + hi) ^ (d & 7));
            bf16x8 vf = *reinterpret_cast<const bf16x8*>((const char*)Vc + d*128 + ch*16);
            ao[dt] = MFMA32(pa[ks], vf, ao[dt]);
          }
        }
        __builtin_amdgcn_s_setprio(0);
      }
      __syncthreads();   // drains vmcnt -> next buffer published; readers done
      cur ^= 1;
    }
    // ---- epilogue ----
    if (lane < 32) alds[w][lane] = 1.0f / lsum;
#pragma unroll
    for (int r = 0; r < 16; r++) {
      int ql = (r & 3) + 8*(r >> 2) + 4*hi;
      float lv = alds[w][ql];
      int t = qlo + ql;
      size_t base = ((size_t)b*TT + t)*CC + h*HD + l31;
#pragma unroll
      for (int dt = 0; dt < 4; dt++)
        yb[base + dt*32] = f2bf(ao[dt][r] * lv);
    }
    __syncthreads();     // alds + LDS buffers reused next phase
  }
#undef STAGE_KV
}

extern "C" void kernel_launch(void* const* d_in, const int* in_sizes, int n_in,
                              void* d_out, int out_size, void* d_ws, size_t ws_size,
                              hipStream_t stream) {
  const float* x  = (const float*)d_in[0];
  const float* wa = (const float*)d_in[1];
  const float* wp = (const float*)d_in[2];
  float* out = (float*)d_out;
  char* ws = (char*)d_ws;
  size_t off = 0;
  unsigned short* xb  = (unsigned short*)(ws + off); off += (size_t)MTOT*CC*2;
  unsigned short* wab = (unsigned short*)(ws + off); off += (size_t)3*CC*CC*2;
  unsigned short* wpb = (unsigned short*)(ws + off); off += (size_t)CC*CC*2;
  unsigned short* qr  = (unsigned short*)(ws + off); off += (size_t)MTOT*CC*2;
  unsigned short* kr  = (unsigned short*)(ws + off); off += (size_t)MTOT*CC*2;
  unsigned short* vt  = (unsigned short*)(ws + off); off += (size_t)MTOT*CC*2;
  unsigned short* yb  = (unsigned short*)(ws + off); off += (size_t)MTOT*CC*2;
  float* tab          = (float*)(ws + off);          off += (size_t)TT*64*2*4;

  k_f2b<<<dim3(16384), dim3(256), 0, stream>>>(x,  xb,  MTOT*CC/4);
  k_f2b<<<dim3(12288), dim3(256), 0, stream>>>(wa, wab, 3*CC*CC/4);
  k_f2b<<<dim3(4096),  dim3(256), 0, stream>>>(wp, wpb, CC*CC/4);
  k_rope_tab<<<dim3(TT), dim3(64), 0, stream>>>(tab);
  k_qkv<<<dim3(768), dim3(512), 0, stream>>>(xb, wab, tab, qr, kr, vt);
  k_attn<<<dim3(256), dim3(512), 0, stream>>>(qr, kr, vt, yb);
  k_proj<<<dim3(256), dim3(512), 0, stream>>>(yb, wpb, out);
}

// Round 15
// 407.524 us; speedup vs baseline: 1.4002x; 1.0084x over previous
//
#include <hip/hip_runtime.h>
#include <stdint.h>

#define TT 2048      // T
#define CC 2048      // C
#define NHEAD 16
#define HD 128
#define NB 4         // batch
#define MTOT (NB*TT) // 8192
#define KD 2048      // GEMM K (both projections)
#define NT 32        // K tiles of 64

typedef __attribute__((ext_vector_type(8))) short bf16x8;
typedef __attribute__((ext_vector_type(4))) float f32x4;
typedef __attribute__((ext_vector_type(16))) float f32x16;
typedef __attribute__((ext_vector_type(4))) unsigned u32x4;

__device__ __forceinline__ unsigned short f2bf(float f) {
  unsigned u = __float_as_uint(f);
  u += 0x7FFF + ((u >> 16) & 1);
  return (unsigned short)(u >> 16);
}
__device__ __forceinline__ float bf2f(unsigned short h) {
  return __uint_as_float(((unsigned)h) << 16);
}

__device__ __forceinline__ void gl_lds16(const unsigned short* g, short* l) {
  __builtin_amdgcn_global_load_lds(
      (const __attribute__((address_space(1))) void*)(g),
      (__attribute__((address_space(3))) void*)(l), 16, 0, 0);
}

#define MFMA16(a, b, c) __builtin_amdgcn_mfma_f32_16x16x32_bf16((a), (b), (c), 0, 0, 0)
#define MFMA32(a, b, c) __builtin_amdgcn_mfma_f32_32x32x16_bf16((a), (b), (c), 0, 0, 0)

#define PRE_MFMA() do { \
  __builtin_amdgcn_s_barrier(); \
  asm volatile("s_waitcnt lgkmcnt(0)" ::: "memory"); \
  __builtin_amdgcn_s_setprio(1); \
} while(0)
#define POST_MFMA() do { \
  __builtin_amdgcn_s_setprio(0); \
  __builtin_amdgcn_s_barrier(); \
  __builtin_amdgcn_sched_barrier(0); \
} while(0)

// ---------------- fp32 -> bf16 cast ----------------
__global__ void k_f2b(const float* __restrict__ in, unsigned short* __restrict__ out, int n4) {
  int i = blockIdx.x * 256 + threadIdx.x;
  if (i >= n4) return;
  float4 v = reinterpret_cast<const float4*>(in)[i];
  ushort4 o;
  o.x = f2bf(v.x); o.y = f2bf(v.y); o.z = f2bf(v.z); o.w = f2bf(v.w);
  reinterpret_cast<ushort4*>(out)[i] = o;
}

// ---------------- RoPE table ----------------
__global__ void k_rope_tab(float* __restrict__ tab) {
  int t = blockIdx.x, i = threadIdx.x;  // 2048 x 64
  double inv = exp2(-(double)i * (13.287712379549449062 / 64.0)); // 10000^(-i/64)
  double ang = (double)t * inv;
  tab[(t*64 + i)*2 + 0] = (float)cos(ang);
  tab[(t*64 + i)*2 + 1] = (float)sin(ang);
}

// ================= 256x256 8-wave 8-PHASE GEMM core (m201 schedule) =================
// C[m][n] = sum_k A[m][k]*B[n][k]; A:[M][2048], B:[N][2048] row-major bf16 bits.
// 512 thr = 8 waves; per-wave output = 2x2 quadrants of (64 rows x 32 cols):
//   rows GM*128 + wm*64 + mi*16, cols GN*128 + wn*32 + ni*16. acc[GM][GN][4][2].
// LDS 128KB: A[db][half]=db*16384+half*8192; B at +32768. Chunk-XOR swizzle.
// Per iteration (2 K-tiles t=2i buf0, t+1 buf1), 8 phases of {ds_read frags |
// stage 1 half-tile | barrier | lgkm0 | 16 MFMA | barrier}:
//  ph1 (t,Q00): read A0(8)+B0(4); s1=A1(t+1)->buf1   [buf1.A1 dead since prev ph7]
//  ph2 (t,Q01): read B1(4);       s2=A0(t+2)->buf0   [A0(t) dead ph1]
//  ph3 (t,Q11): read A1(8);       s3=B0(t+2)         [B0(t) dead ph1; regs cached]
//  ph4 (t,Q10): no reads;         s4=B1(t+2); vmcnt(6)  [B1(t) dead ph2]
//  ph5 (t+1,Q00): read A0b+B0b;   s5=A1(t+2)         [A1(t) dead ph3]
//  ph6 (t+1,Q01): read B1b;       s6=A0(t+3)->buf1   [A0(t+1) dead ph5]
//  ph7 (t+1,Q11): read A1b;       s7=B0(t+3)         [B0(t+1) dead ph5]
//  ph8 (t+1,Q10): no reads;       s8=B1(t+3); vmcnt(6)  [B1(t+1) dead ph6]
// FIFO guarantees: ph4's vmcnt(6) lands {prev s6,s7,s8, s1} (feeds ph5-7);
// ph8's lands {s2..s5} (feeds next ph1-3). Last iter: only s1, vmcnt(0).
// Per-element accumulation order identical to 2-phase kk-split (absmax-invariant).
__device__ __forceinline__ void gemm256_core(
    const unsigned short* __restrict__ Ag,
    const unsigned short* __restrict__ Bg,
    int m0, int n0, short* lds, f32x4 (&acc)[2][2][4][2])
{
  const int tid = threadIdx.x;
  const int wid = tid >> 6, lane = tid & 63;
  const int wm = wid >> 2, wn = wid & 3;
  const int r15 = lane & 15, hi4 = lane >> 4;
  const int srow = wid*8 + (lane >> 3);
  const int schunk = (lane & 7) ^ (lane >> 3);

  const f32x4 fz = {0.f, 0.f, 0.f, 0.f};
#pragma unroll
  for (int p = 0; p < 2; p++)
#pragma unroll
    for (int q = 0; q < 2; q++)
#pragma unroll
      for (int i = 0; i < 4; i++)
#pragma unroll
        for (int j = 0; j < 2; j++) acc[p][q][i][j] = fz;

  int aoff[4][2];   // within a 128x64 half (shorts)
#pragma unroll
  for (int mi = 0; mi < 4; mi++)
#pragma unroll
    for (int kk = 0; kk < 2; kk++) {
      int row = wm*64 + mi*16 + r15;
      aoff[mi][kk] = row*64 + (((kk*4 + hi4) ^ (row & 7))*8);
    }
  int boff[2][2];
#pragma unroll
  for (int ni = 0; ni < 2; ni++)
#pragma unroll
    for (int kk = 0; kk < 2; kk++) {
      int row = wn*32 + ni*16 + r15;
      boff[ni][kk] = row*64 + (((kk*4 + hi4) ^ (row & 7))*8);
    }

  short* A0  = lds;            short* A1  = lds + 8192;
  short* A0b = lds + 16384;    short* A1b = lds + 24576;
  short* B0l = lds + 32768;    short* B1l = lds + 40960;
  short* B0b = lds + 49152;    short* B1b = lds + 57344;

#define STAGE(G, L, GROW0, KT) do { \
    gl_lds16((G) + (size_t)((GROW0) + srow)*KD + (KT) + schunk*8, (L) + wid*512); \
    gl_lds16((G) + (size_t)((GROW0) + 64 + srow)*KD + (KT) + schunk*8, (L) + 4096 + wid*512); \
  } while(0)

  // prologue: tile0 (all 4 halves) + tile1 (A0,B0,B1); A1(1) staged by iter0's s1
  STAGE(Ag, A0,  m0,       0);
  STAGE(Bg, B0l, n0,       0);
  STAGE(Bg, B1l, n0 + 128, 0);
  STAGE(Ag, A1,  m0 + 128, 0);
  STAGE(Ag, A0b, m0,       64);
  STAGE(Bg, B0b, n0,       64);
  STAGE(Bg, B1b, n0 + 128, 64);
  asm volatile("s_waitcnt vmcnt(0)" ::: "memory");
  __builtin_amdgcn_s_barrier();
  __builtin_amdgcn_sched_barrier(0);

  bf16x8 a[4][2], b0[2][2], b1[2][2];

#pragma unroll 1
  for (int it = 0; it < 16; it++) {
    const int kt = it*128;
    const bool stP = (it < 15);

    // ---- ph1: tile t, Q(0,0): A0 frags + B0 frags; s1 = A1(t+1) ----
#pragma unroll
    for (int mi = 0; mi < 4; mi++) {
      a[mi][0] = *reinterpret_cast<const bf16x8*>(A0 + aoff[mi][0]);
      a[mi][1] = *reinterpret_cast<const bf16x8*>(A0 + aoff[mi][1]);
    }
#pragma unroll
    for (int ni = 0; ni < 2; ni++) {
      b0[ni][0] = *reinterpret_cast<const bf16x8*>(B0l + boff[ni][0]);
      b0[ni][1] = *reinterpret_cast<const bf16x8*>(B0l + boff[ni][1]);
    }
    STAGE(Ag, A1b, m0 + 128, kt + 64);
    PRE_MFMA();
#pragma unroll
    for (int mi = 0; mi < 4; mi++)
#pragma unroll
      for (int ni = 0; ni < 2; ni++) {
        acc[0][0][mi][ni] = MFMA16(a[mi][0], b0[ni][0], acc[0][0][mi][ni]);
        acc[0][0][mi][ni] = MFMA16(a[mi][1], b0[ni][1], acc[0][0][mi][ni]);
      }
    POST_MFMA();

    // ---- ph2: Q(0,1): B1 frags; s2 = A0(t+2) ----
#pragma unroll
    for (int ni = 0; ni < 2; ni++) {
      b1[ni][0] = *reinterpret_cast<const bf16x8*>(B1l + boff[ni][0]);
      b1[ni][1] = *reinterpret_cast<const bf16x8*>(B1l + boff[ni][1]);
    }
    if (stP) STAGE(Ag, A0, m0, kt + 128);
    PRE_MFMA();
#pragma unroll
    for (int mi = 0; mi < 4; mi++)
#pragma unroll
      for (int ni = 0; ni < 2; ni++) {
        acc[0][1][mi][ni] = MFMA16(a[mi][0], b1[ni][0], acc[0][1][mi][ni]);
        acc[0][1][mi][ni] = MFMA16(a[mi][1], b1[ni][1], acc[0][1][mi][ni]);
      }
    POST_MFMA();

    // ---- ph3: Q(1,1): A1 frags; s3 = B0(t+2) ----
#pragma unroll
    for (int mi = 0; mi < 4; mi++) {
      a[mi][0] = *reinterpret_cast<const bf16x8*>(A1 + aoff[mi][0]);
      a[mi][1] = *reinterpret_cast<const bf16x8*>(A1 + aoff[mi][1]);
    }
    if (stP) STAGE(Bg, B0l, n0, kt + 128);
    PRE_MFMA();
#pragma unroll
    for (int mi = 0; mi < 4; mi++)
#pragma unroll
      for (int ni = 0; ni < 2; ni++) {
        acc[1][1][mi][ni] = MFMA16(a[mi][0], b1[ni][0], acc[1][1][mi][ni]);
        acc[1][1][mi][ni] = MFMA16(a[mi][1], b1[ni][1], acc[1][1][mi][ni]);
      }
    POST_MFMA();

    // ---- ph4: Q(1,0): no reads (a=A1, b0 cached); s4 = B1(t+2); vmcnt ----
    if (stP) STAGE(Bg, B1l, n0 + 128, kt + 128);
    if (stP) asm volatile("s_waitcnt vmcnt(6)" ::: "memory");
    else     asm volatile("s_waitcnt vmcnt(0)" ::: "memory");
    PRE_MFMA();
#pragma unroll
    for (int mi = 0; mi < 4; mi++)
#pragma unroll
      for (int ni = 0; ni < 2; ni++) {
        acc[1][0][mi][ni] = MFMA16(a[mi][0], b0[ni][0], acc[1][0][mi][ni]);
        acc[1][0][mi][ni] = MFMA16(a[mi][1], b0[ni][1], acc[1][0][mi][ni]);
      }
    POST_MFMA();

    // ---- ph5: tile t+1, Q(0,0): A0b + B0b; s5 = A1(t+2) ----
#pragma unroll
    for (int mi = 0; mi < 4; mi++) {
      a[mi][0] = *reinterpret_cast<const bf16x8*>(A0b + aoff[mi][0]);
      a[mi][1] = *reinterpret_cast<const bf16x8*>(A0b + aoff[mi][1]);
    }
#pragma unroll
    for (int ni = 0; ni < 2; ni++) {
      b0[ni][0] = *reinterpret_cast<const bf16x8*>(B0b + boff[ni][0]);
      b0[ni][1] = *reinterpret_cast<const bf16x8*>(B0b + boff[ni][1]);
    }
    if (stP) STAGE(Ag, A1, m0 + 128, kt + 128);
    PRE_MFMA();
#pragma unroll
    for (int mi = 0; mi < 4; mi++)
#pragma unroll
      for (int ni = 0; ni < 2; ni++) {
        acc[0][0][mi][ni] = MFMA16(a[mi][0], b0[ni][0], acc[0][0][mi][ni]);
        acc[0][0][mi][ni] = MFMA16(a[mi][1], b0[ni][1], acc[0][0][mi][ni]);
      }
    POST_MFMA();

    // ---- ph6: Q(0,1): B1b; s6 = A0(t+3) ----
#pragma unroll
    for (int ni = 0; ni < 2; ni++) {
      b1[ni][0] = *reinterpret_cast<const bf16x8*>(B1b + boff[ni][0]);
      b1[ni][1] = *reinterpret_cast<const bf16x8*>(B1b + boff[ni][1]);
    }
    if (stP) STAGE(Ag, A0b, m0, kt + 192);
    PRE_MFMA();
#pragma unroll
    for (int mi = 0; mi < 4; mi++)
#pragma unroll
      for (int ni = 0; ni < 2; ni++) {
        acc[0][1][mi][ni] = MFMA16(a[mi][0], b1[ni][0], acc[0][1][mi][ni]);
        acc[0][1][mi][ni] = MFMA16(a[mi][1], b1[ni][1], acc[0][1][mi][ni]);
      }
    POST_MFMA();

    // ---- ph7: Q(1,1): A1b; s7 = B0(t+3) ----
#pragma unroll
    for (int mi = 0; mi < 4; mi++) {
      a[mi][0] = *reinterpret_cast<const bf16x8*>(A1b + aoff[mi][0]);
      a[mi][1] = *reinterpret_cast<const bf16x8*>(A1b + aoff[mi][1]);
    }
    if (stP) STAGE(Bg, B0b, n0, kt + 192);
    PRE_MFMA();
#pragma unroll
    for (int mi = 0; mi < 4; mi++)
#pragma unroll
      for (int ni = 0; ni < 2; ni++) {
        acc[1][1][mi][ni] = MFMA16(a[mi][0], b1[ni][0], acc[1][1][mi][ni]);
        acc[1][1][mi][ni] = MFMA16(a[mi][1], b1[ni][1], acc[1][1][mi][ni]);
      }
    POST_MFMA();

    // ---- ph8: Q(1,0): no reads; s8 = B1(t+3); vmcnt ----
    if (stP) STAGE(Bg, B1b, n0 + 128, kt + 192);
    if (stP) asm volatile("s_waitcnt vmcnt(6)" ::: "memory");
    else     asm volatile("s_waitcnt vmcnt(0)" ::: "memory");
    PRE_MFMA();
#pragma unroll
    for (int mi = 0; mi < 4; mi++)
#pragma unroll
      for (int ni = 0; ni < 2; ni++) {
        acc[1][0][mi][ni] = MFMA16(a[mi][0], b0[ni][0], acc[1][0][mi][ni]);
        acc[1][0][mi][ni] = MFMA16(a[mi][1], b0[ni][1], acc[1][0][mi][ni]);
      }
    POST_MFMA();
  }
#undef STAGE
}

// ---------------- QKV projection + scatter + fused RoPE ----------------
__global__ __launch_bounds__(512, 2) void k_qkv(
    const unsigned short* __restrict__ xb,
    const unsigned short* __restrict__ wab,
    const float* __restrict__ tab,
    unsigned short* __restrict__ qr,
    unsigned short* __restrict__ kr,
    unsigned short* __restrict__ vt)
{
  __shared__ __align__(16) short lds[65536];
  f32x4 acc[2][2][4][2];
  int bid = blockIdx.x;                      // 768 blocks
  int swz = (bid & 7)*96 + (bid >> 3);       // bijective XCD swizzle
  int m0 = (swz / 24)*256, n0 = (swz % 24)*256;
  gemm256_core(xb, wab, m0, n0, lds, acc);

  int tid = threadIdx.x, wid = tid >> 6, lane = tid & 63;
  int wm = wid >> 2, wn = wid & 3, r15 = lane & 15, hi4 = lane >> 4;
  int which = n0 >> 11;            // 0=q, 1=k, 2=v (tiles never cross sections)
#pragma unroll
  for (int GM = 0; GM < 2; GM++) {
#pragma unroll
    for (int mi = 0; mi < 4; mi++) {
      int m_base = m0 + GM*128 + wm*64 + mi*16 + hi4*4;
      int b = m_base >> 11;
      int t0 = m_base & (TT - 1);
#pragma unroll
      for (int GN = 0; GN < 2; GN++) {
        int h = ((n0 & 2047) >> 7) + GN;
#pragma unroll
        for (int ni = 0; ni < 2; ni++) {
          int d = wn*32 + ni*16 + r15;
          if (which == 2) {
            ushort4 pv;
            pv.x = f2bf(acc[GM][GN][mi][ni][0]); pv.y = f2bf(acc[GM][GN][mi][ni][1]);
            pv.z = f2bf(acc[GM][GN][mi][ni][2]); pv.w = f2bf(acc[GM][GN][mi][ni][3]);
            *reinterpret_cast<ushort4*>(vt + ((size_t)((b*NHEAD + h)*HD + d))*TT + t0) = pv;
          } else {
            unsigned short* dst = (which == 0) ? qr : kr;
            size_t base = ((size_t)(b*NHEAD + h)*TT + t0)*HD + d;
            int j = d >> 1;
            bool odd = (d & 1);
#pragma unroll
            for (int r = 0; r < 4; r++) {
              float v = acc[GM][GN][mi][ni][r];
              float pv = __shfl_xor(v, 1);
              float2 cs = *reinterpret_cast<const float2*>(tab + ((size_t)(t0 + r)*64 + j)*2);
              float res = odd ? (pv*cs.y + v*cs.x) : (v*cs.x - pv*cs.y);
              dst[base + (size_t)r*HD] = f2bf(res);
            }
          }
        }
      }
    }
  }
}

// ---------------- output projection ----------------
__global__ __launch_bounds__(512, 2) void k_proj(
    const unsigned short* __restrict__ yb,
    const unsigned short* __restrict__ wpb,
    float* __restrict__ out)
{
  __shared__ __align__(16) short lds[65536];
  f32x4 acc[2][2][4][2];
  int bid = blockIdx.x;                      // 256 blocks
  int swz = (bid & 7)*32 + (bid >> 3);
  int m0 = (swz / 8)*256, n0 = (swz % 8)*256;
  gemm256_core(yb, wpb, m0, n0, lds, acc);

  int tid = threadIdx.x, wid = tid >> 6, lane = tid & 63;
  int wm = wid >> 2, wn = wid & 3, r15 = lane & 15, hi4 = lane >> 4;
#pragma unroll
  for (int GM = 0; GM < 2; GM++) {
#pragma unroll
    for (int mi = 0; mi < 4; mi++) {
      int m = m0 + GM*128 + wm*64 + mi*16 + hi4*4;
#pragma unroll
      for (int GN = 0; GN < 2; GN++) {
#pragma unroll
        for (int ni = 0; ni < 2; ni++) {
          int n = n0 + GN*128 + wn*32 + ni*16 + r15;
#pragma unroll
          for (int r = 0; r < 4; r++)
            out[(size_t)(m + r)*CC + n] = acc[GM][GN][mi][ni][r];
        }
      }
    }
  }
}

// ---------------- causal flash attention: swapped-QK^T 32x32, in-register softmax ----------------
// (unchanged from round 14 — 8-wave blocks, passed at absmax 0.015625)
__global__ __launch_bounds__(512, 1) void k_attn(
    const unsigned short* __restrict__ qr,
    const unsigned short* __restrict__ kr,
    const unsigned short* __restrict__ vt,
    unsigned short* __restrict__ yb)
{
  __shared__ __align__(16) short Ks[2][64*128];   // [buf][kv][d], chunk-XOR swizzled
  __shared__ __align__(16) short Vs[2][128*64];   // [buf][d][kv], chunk-XOR swizzled
  __shared__ float alds[8][32];                   // per-wave alpha/linv broadcast
  int bid = blockIdx.x;
  int bh = bid & 63, pr = bid >> 6;               // pr 0..3
  int tid = threadIdx.x, w = tid >> 6, lane = tid & 63;
  int l31 = lane & 31, hi = lane >> 5;
  const unsigned short* qg = qr + (size_t)bh*TT*HD;
  const unsigned short* kg = kr + (size_t)bh*TT*HD;
  const unsigned short* vg = vt + (size_t)bh*HD*TT;
  const float scale = 0.08838834764831845f; // 1/sqrt(128)
  int b = bh >> 4, h = bh & 15;

  int ksoff[2], vsoff[2];
#pragma unroll
  for (int i = 0; i < 2; i++) {
    int c = w*2 + i;
    int rK = c*4 + (lane >> 4);
    int cK = (lane & 15) ^ (rK & 7);
    ksoff[i] = rK*HD + cK*8;
    int dV = c*8 + (lane >> 3);
    int cV = (lane & 7) ^ (dV & 7);
    vsoff[i] = dV*TT + cV*8;
  }

#define STAGE_KV(BUF, KV0) do { \
    _Pragma("unroll") \
    for (int i_ = 0; i_ < 2; i_++) { \
      gl_lds16(kg + (size_t)(KV0)*HD + ksoff[i_], &Ks[BUF][(w*2 + i_)*512]); \
      gl_lds16(vg + (KV0) + vsoff[i_],            &Vs[BUF][(w*2 + i_)*512]); \
    } \
  } while(0)

#pragma unroll 1
  for (int ph = 0; ph < 2; ph++) {
    int qb = ph ? (7 - pr) : pr;
    int qlo = qb*256 + w*32;
    int qgi = qlo + l31;
    bf16x8 qf[8];
#pragma unroll
    for (int kk = 0; kk < 8; kk++)
      qf[kk] = *reinterpret_cast<const bf16x8*>(qg + (size_t)qgi*HD + kk*16 + hi*8);

    f32x16 ao[4];
#pragma unroll
    for (int dt = 0; dt < 4; dt++)
#pragma unroll
      for (int r = 0; r < 16; r++) ao[dt][r] = 0.f;
    float mrow = -3.0e38f, lsum = 0.f;
    int ntiles = 4*qb + 4;

    STAGE_KV(0, 0);
    __syncthreads();
    int cur = 0;

#pragma unroll 1
    for (int it = 0; it < ntiles; ++it) {
      int kv0 = it*64;
      if (it + 1 < ntiles) STAGE_KV(cur ^ 1, kv0 + 64);
      if (kv0 <= qlo + 31) {
        const short* Kc = Ks[cur];
        const short* Vc = Vs[cur];
        bool full = (kv0 + 63 <= qlo);
        f32x16 s0, s1;
#pragma unroll
        for (int r = 0; r < 16; r++) { s0[r] = 0.f; s1[r] = 0.f; }
        __builtin_amdgcn_s_setprio(1);
#pragma unroll
        for (int kk = 0; kk < 8; kk++) {
          int row0 = l31, row1 = 32 + l31;
          int ch0 = ((2*kk + hi) ^ (row0 & 7));
          int ch1 = ((2*kk + hi) ^ (row1 & 7));
          bf16x8 kf0 = *reinterpret_cast<const bf16x8*>((const char*)Kc + row0*256 + ch0*16);
          bf16x8 kf1 = *reinterpret_cast<const bf16x8*>((const char*)Kc + row1*256 + ch1*16);
          s0 = MFMA32(kf0, qf[kk], s0);
          s1 = MFMA32(kf1, qf[kk], s1);
        }
        __builtin_amdgcn_s_setprio(0);
        float p[32];
#pragma unroll
        for (int r = 0; r < 16; r++) {
          int kvl = (r & 3) + 8*(r >> 2) + 4*hi;
          float v0 = s0[r]*scale, v1 = s1[r]*scale;
          if (!full) {
            v0 = (kv0 + kvl      <= qgi) ? v0 : -3.0e38f;
            v1 = (kv0 + 32 + kvl <= qgi) ? v1 : -3.0e38f;
          }
          p[r] = v0; p[16 + r] = v1;
        }
        float t16[16];
#pragma unroll
        for (int i = 0; i < 16; i++) t16[i] = fmaxf(p[i], p[i + 16]);
#pragma unroll
        for (int i = 0; i < 8; i++) t16[i] = fmaxf(t16[i], t16[i + 8]);
#pragma unroll
        for (int i = 0; i < 4; i++) t16[i] = fmaxf(t16[i], t16[i + 4]);
        float mx = fmaxf(fmaxf(t16[0], t16[1]), fmaxf(t16[2], t16[3]));
        mx = fmaxf(mx, __shfl_xor(mx, 32));
        bool defer = __all(mx <= mrow + 8.f);
        if (!defer) {
          float mnew = fmaxf(mrow, mx);
          float alpha = __expf(mrow - mnew);
          mrow = mnew;
          lsum *= alpha;
          if (lane < 32) alds[w][lane] = alpha;
#pragma unroll
          for (int r = 0; r < 16; r++) {
            int ql = (r & 3) + 8*(r >> 2) + 4*hi;
            float av = alds[w][ql];
#pragma unroll
            for (int dt = 0; dt < 4; dt++) ao[dt][r] *= av;
          }
        }
#pragma unroll
        for (int i = 0; i < 32; i++) p[i] = __expf(p[i] - mrow);
#pragma unroll
        for (int i = 0; i < 16; i++) t16[i] = p[i] + p[i + 16];
#pragma unroll
        for (int i = 0; i < 8; i++) t16[i] = t16[i] + t16[i + 8];
#pragma unroll
        for (int i = 0; i < 4; i++) t16[i] = t16[i] + t16[i + 4];
        float rs = (t16[0] + t16[1]) + (t16[2] + t16[3]);
        rs += __shfl_xor(rs, 32);
        lsum += rs;
        bf16x8 pa[4];
#pragma unroll
        for (int ks = 0; ks < 4; ks++) {
          const int base = (ks >> 1)*16 + (ks & 1)*8;
          unsigned a0, a1, b0, b1;
          asm("v_cvt_pk_bf16_f32 %0, %1, %2" : "=v"(a0) : "v"(p[base + 0]), "v"(p[base + 1]));
          asm("v_cvt_pk_bf16_f32 %0, %1, %2" : "=v"(a1) : "v"(p[base + 2]), "v"(p[base + 3]));
          asm("v_cvt_pk_bf16_f32 %0, %1, %2" : "=v"(b0) : "v"(p[base + 4]), "v"(p[base + 5]));
          asm("v_cvt_pk_bf16_f32 %0, %1, %2" : "=v"(b1) : "v"(p[base + 6]), "v"(p[base + 7]));
          unsigned sa0 = (unsigned)__shfl_xor((int)a0, 32);
          unsigned sa1 = (unsigned)__shfl_xor((int)a1, 32);
          unsigned sb0 = (unsigned)__shfl_xor((int)b0, 32);
          unsigned sb1 = (unsigned)__shfl_xor((int)b1, 32);
          u32x4 pw;
          pw.x = hi ? sb0 : a0;
          pw.y = hi ? sb1 : a1;
          pw.z = hi ? b0 : sa0;
          pw.w = hi ? b1 : sa1;
          pa[ks] = __builtin_bit_cast(bf16x8, pw);
        }
        __builtin_amdgcn_s_setprio(1);
#pragma unroll
        for (int dt = 0; dt < 4; dt++) {
          int d = dt*32 + l31;
#pragma unroll
          for (int ks = 0; ks < 4; ks++) {
            int ch = ((2*ks + hi) ^ (d & 7));
            bf16x8 vf = *reinterpret_cast<const bf16x8*>((const char*)Vc + d*128 + ch*16);
            ao[dt] = MFMA32(pa[ks], vf, ao[dt]);
          }
        }
        __builtin_amdgcn_s_setprio(0);
      }
      __syncthreads();
      cur ^= 1;
    }
    if (lane < 32) alds[w][lane] = 1.0f / lsum;
#pragma unroll
    for (int r = 0; r < 16; r++) {
      int ql = (r & 3) + 8*(r >> 2) + 4*hi;
      float lv = alds[w][ql];
      int t = qlo + ql;
      size_t base = ((size_t)b*TT + t)*CC + h*HD + l31;
#pragma unroll
      for (int dt = 0; dt < 4; dt++)
        yb[base + dt*32] = f2bf(ao[dt][r] * lv);
    }
    __syncthreads();
  }
#undef STAGE_KV
}

extern "C" void kernel_launch(void* const* d_in, const int* in_sizes, int n_in,
                              void* d_out, int out_size, void* d_ws, size_t ws_size,
                              hipStream_t stream) {
  const float* x  = (const float*)d_in[0];
  const float* wa = (const float*)d_in[1];
  const float* wp = (const float*)d_in[2];
  float* out = (float*)d_out;
  char* ws = (char*)d_ws;
  size_t off = 0;
  unsigned short* xb  = (unsigned short*)(ws + off); off += (size_t)MTOT*CC*2;
  unsigned short* wab = (unsigned short*)(ws + off); off += (size_t)3*CC*CC*2;
  unsigned short* wpb = (unsigned short*)(ws + off); off += (size_t)CC*CC*2;
  unsigned short* qr  = (unsigned short*)(ws + off); off += (size_t)MTOT*CC*2;
  unsigned short* kr  = (unsigned short*)(ws + off); off += (size_t)MTOT*CC*2;
  unsigned short* vt  = (unsigned short*)(ws + off); off += (size_t)MTOT*CC*2;
  unsigned short* yb  = (unsigned short*)(ws + off); off += (size_t)MTOT*CC*2;
  float* tab          = (float*)(ws + off);          off += (size_t)TT*64*2*4;

  k_f2b<<<dim3(16384), dim3(256), 0, stream>>>(x,  xb,  MTOT*CC/4);
  k_f2b<<<dim3(12288), dim3(256), 0, stream>>>(wa, wab, 3*CC*CC/4);
  k_f2b<<<dim3(4096),  dim3(256), 0, stream>>>(wp, wpb, CC*CC/4);
  k_rope_tab<<<dim3(TT), dim3(64), 0, stream>>>(tab);
  k_qkv<<<dim3(768), dim3(512), 0, stream>>>(xb, wab, tab, qr, kr, vt);
  k_attn<<<dim3(256), dim3(512), 0, stream>>>(qr, kr, vt, yb);
  k_proj<<<dim3(256), dim3(512), 0, stream>>>(yb, wpb, out);
}

// Round 16
// 401.440 us; speedup vs baseline: 1.4214x; 1.0152x over previous
//
#include <hip/hip_runtime.h>
#include <stdint.h>

#define TT 2048      // T
#define CC 2048      // C
#define NHEAD 16
#define HD 128
#define NB 4         // batch
#define MTOT (NB*TT) // 8192
#define KD 2048      // GEMM K (both projections)
#define NT 32        // K tiles of 64

typedef __attribute__((ext_vector_type(8))) short bf16x8;
typedef __attribute__((ext_vector_type(4))) float f32x4;
typedef __attribute__((ext_vector_type(16))) float f32x16;
typedef __attribute__((ext_vector_type(4))) unsigned u32x4;

__device__ __forceinline__ unsigned short f2bf(float f) {
  unsigned u = __float_as_uint(f);
  u += 0x7FFF + ((u >> 16) & 1);
  return (unsigned short)(u >> 16);
}
__device__ __forceinline__ float bf2f(unsigned short h) {
  return __uint_as_float(((unsigned)h) << 16);
}

__device__ __forceinline__ void gl_lds16(const unsigned short* g, short* l) {
  __builtin_amdgcn_global_load_lds(
      (const __attribute__((address_space(1))) void*)(g),
      (__attribute__((address_space(3))) void*)(l), 16, 0, 0);
}

#define MFMA16(a, b, c) __builtin_amdgcn_mfma_f32_16x16x32_bf16((a), (b), (c), 0, 0, 0)
#define MFMA32(a, b, c) __builtin_amdgcn_mfma_f32_32x32x16_bf16((a), (b), (c), 0, 0, 0)

#define PRE_MFMA() do { \
  __builtin_amdgcn_s_barrier(); \
  asm volatile("s_waitcnt lgkmcnt(0)" ::: "memory"); \
  __builtin_amdgcn_s_setprio(1); \
} while(0)
#define POST_MFMA() do { \
  __builtin_amdgcn_s_setprio(0); \
  __builtin_amdgcn_s_barrier(); \
  __builtin_amdgcn_sched_barrier(0); \
} while(0)

// ---------------- fp32 -> bf16 cast ----------------
__global__ void k_f2b(const float* __restrict__ in, unsigned short* __restrict__ out, int n4) {
  int i = blockIdx.x * 256 + threadIdx.x;
  if (i >= n4) return;
  float4 v = reinterpret_cast<const float4*>(in)[i];
  ushort4 o;
  o.x = f2bf(v.x); o.y = f2bf(v.y); o.z = f2bf(v.z); o.w = f2bf(v.w);
  reinterpret_cast<ushort4*>(out)[i] = o;
}

// ---------------- RoPE table ----------------
__global__ void k_rope_tab(float* __restrict__ tab) {
  int t = blockIdx.x, i = threadIdx.x;  // 2048 x 64
  double inv = exp2(-(double)i * (13.287712379549449062 / 64.0)); // 10000^(-i/64)
  double ang = (double)t * inv;
  tab[(t*64 + i)*2 + 0] = (float)cos(ang);
  tab[(t*64 + i)*2 + 1] = (float)sin(ang);
}

// ================= 256x256 8-wave 8-PHASE GEMM core (m201 schedule) =================
// (unchanged from round 15; see its hazard ledger comment)
__device__ __forceinline__ void gemm256_core(
    const unsigned short* __restrict__ Ag,
    const unsigned short* __restrict__ Bg,
    int m0, int n0, short* lds, f32x4 (&acc)[2][2][4][2])
{
  const int tid = threadIdx.x;
  const int wid = tid >> 6, lane = tid & 63;
  const int wm = wid >> 2, wn = wid & 3;
  const int r15 = lane & 15, hi4 = lane >> 4;
  const int srow = wid*8 + (lane >> 3);
  const int schunk = (lane & 7) ^ (lane >> 3);

  const f32x4 fz = {0.f, 0.f, 0.f, 0.f};
#pragma unroll
  for (int p = 0; p < 2; p++)
#pragma unroll
    for (int q = 0; q < 2; q++)
#pragma unroll
      for (int i = 0; i < 4; i++)
#pragma unroll
        for (int j = 0; j < 2; j++) acc[p][q][i][j] = fz;

  int aoff[4][2];   // within a 128x64 half (shorts)
#pragma unroll
  for (int mi = 0; mi < 4; mi++)
#pragma unroll
    for (int kk = 0; kk < 2; kk++) {
      int row = wm*64 + mi*16 + r15;
      aoff[mi][kk] = row*64 + (((kk*4 + hi4) ^ (row & 7))*8);
    }
  int boff[2][2];
#pragma unroll
  for (int ni = 0; ni < 2; ni++)
#pragma unroll
    for (int kk = 0; kk < 2; kk++) {
      int row = wn*32 + ni*16 + r15;
      boff[ni][kk] = row*64 + (((kk*4 + hi4) ^ (row & 7))*8);
    }

  short* A0  = lds;            short* A1  = lds + 8192;
  short* A0b = lds + 16384;    short* A1b = lds + 24576;
  short* B0l = lds + 32768;    short* B1l = lds + 40960;
  short* B0b = lds + 49152;    short* B1b = lds + 57344;

#define STAGE(G, L, GROW0, KT) do { \
    gl_lds16((G) + (size_t)((GROW0) + srow)*KD + (KT) + schunk*8, (L) + wid*512); \
    gl_lds16((G) + (size_t)((GROW0) + 64 + srow)*KD + (KT) + schunk*8, (L) + 4096 + wid*512); \
  } while(0)

  // prologue: tile0 (all 4 halves) + tile1 (A0,B0,B1); A1(1) staged by iter0's s1
  STAGE(Ag, A0,  m0,       0);
  STAGE(Bg, B0l, n0,       0);
  STAGE(Bg, B1l, n0 + 128, 0);
  STAGE(Ag, A1,  m0 + 128, 0);
  STAGE(Ag, A0b, m0,       64);
  STAGE(Bg, B0b, n0,       64);
  STAGE(Bg, B1b, n0 + 128, 64);
  asm volatile("s_waitcnt vmcnt(0)" ::: "memory");
  __builtin_amdgcn_s_barrier();
  __builtin_amdgcn_sched_barrier(0);

  bf16x8 a[4][2], b0[2][2], b1[2][2];

#pragma unroll 1
  for (int it = 0; it < 16; it++) {
    const int kt = it*128;
    const bool stP = (it < 15);

    // ---- ph1: tile t, Q(0,0): A0 frags + B0 frags; s1 = A1(t+1) ----
#pragma unroll
    for (int mi = 0; mi < 4; mi++) {
      a[mi][0] = *reinterpret_cast<const bf16x8*>(A0 + aoff[mi][0]);
      a[mi][1] = *reinterpret_cast<const bf16x8*>(A0 + aoff[mi][1]);
    }
#pragma unroll
    for (int ni = 0; ni < 2; ni++) {
      b0[ni][0] = *reinterpret_cast<const bf16x8*>(B0l + boff[ni][0]);
      b0[ni][1] = *reinterpret_cast<const bf16x8*>(B0l + boff[ni][1]);
    }
    STAGE(Ag, A1b, m0 + 128, kt + 64);
    PRE_MFMA();
#pragma unroll
    for (int mi = 0; mi < 4; mi++)
#pragma unroll
      for (int ni = 0; ni < 2; ni++) {
        acc[0][0][mi][ni] = MFMA16(a[mi][0], b0[ni][0], acc[0][0][mi][ni]);
        acc[0][0][mi][ni] = MFMA16(a[mi][1], b0[ni][1], acc[0][0][mi][ni]);
      }
    POST_MFMA();

    // ---- ph2: Q(0,1): B1 frags; s2 = A0(t+2) ----
#pragma unroll
    for (int ni = 0; ni < 2; ni++) {
      b1[ni][0] = *reinterpret_cast<const bf16x8*>(B1l + boff[ni][0]);
      b1[ni][1] = *reinterpret_cast<const bf16x8*>(B1l + boff[ni][1]);
    }
    if (stP) STAGE(Ag, A0, m0, kt + 128);
    PRE_MFMA();
#pragma unroll
    for (int mi = 0; mi < 4; mi++)
#pragma unroll
      for (int ni = 0; ni < 2; ni++) {
        acc[0][1][mi][ni] = MFMA16(a[mi][0], b1[ni][0], acc[0][1][mi][ni]);
        acc[0][1][mi][ni] = MFMA16(a[mi][1], b1[ni][1], acc[0][1][mi][ni]);
      }
    POST_MFMA();

    // ---- ph3: Q(1,1): A1 frags; s3 = B0(t+2) ----
#pragma unroll
    for (int mi = 0; mi < 4; mi++) {
      a[mi][0] = *reinterpret_cast<const bf16x8*>(A1 + aoff[mi][0]);
      a[mi][1] = *reinterpret_cast<const bf16x8*>(A1 + aoff[mi][1]);
    }
    if (stP) STAGE(Bg, B0l, n0, kt + 128);
    PRE_MFMA();
#pragma unroll
    for (int mi = 0; mi < 4; mi++)
#pragma unroll
      for (int ni = 0; ni < 2; ni++) {
        acc[1][1][mi][ni] = MFMA16(a[mi][0], b1[ni][0], acc[1][1][mi][ni]);
        acc[1][1][mi][ni] = MFMA16(a[mi][1], b1[ni][1], acc[1][1][mi][ni]);
      }
    POST_MFMA();

    // ---- ph4: Q(1,0): no reads (a=A1, b0 cached); s4 = B1(t+2); vmcnt ----
    if (stP) STAGE(Bg, B1l, n0 + 128, kt + 128);
    if (stP) asm volatile("s_waitcnt vmcnt(6)" ::: "memory");
    else     asm volatile("s_waitcnt vmcnt(0)" ::: "memory");
    PRE_MFMA();
#pragma unroll
    for (int mi = 0; mi < 4; mi++)
#pragma unroll
      for (int ni = 0; ni < 2; ni++) {
        acc[1][0][mi][ni] = MFMA16(a[mi][0], b0[ni][0], acc[1][0][mi][ni]);
        acc[1][0][mi][ni] = MFMA16(a[mi][1], b0[ni][1], acc[1][0][mi][ni]);
      }
    POST_MFMA();

    // ---- ph5: tile t+1, Q(0,0): A0b + B0b; s5 = A1(t+2) ----
#pragma unroll
    for (int mi = 0; mi < 4; mi++) {
      a[mi][0] = *reinterpret_cast<const bf16x8*>(A0b + aoff[mi][0]);
      a[mi][1] = *reinterpret_cast<const bf16x8*>(A0b + aoff[mi][1]);
    }
#pragma unroll
    for (int ni = 0; ni < 2; ni++) {
      b0[ni][0] = *reinterpret_cast<const bf16x8*>(B0b + boff[ni][0]);
      b0[ni][1] = *reinterpret_cast<const bf16x8*>(B0b + boff[ni][1]);
    }
    if (stP) STAGE(Ag, A1, m0 + 128, kt + 128);
    PRE_MFMA();
#pragma unroll
    for (int mi = 0; mi < 4; mi++)
#pragma unroll
      for (int ni = 0; ni < 2; ni++) {
        acc[0][0][mi][ni] = MFMA16(a[mi][0], b0[ni][0], acc[0][0][mi][ni]);
        acc[0][0][mi][ni] = MFMA16(a[mi][1], b0[ni][1], acc[0][0][mi][ni]);
      }
    POST_MFMA();

    // ---- ph6: Q(0,1): B1b; s6 = A0(t+3) ----
#pragma unroll
    for (int ni = 0; ni < 2; ni++) {
      b1[ni][0] = *reinterpret_cast<const bf16x8*>(B1b + boff[ni][0]);
      b1[ni][1] = *reinterpret_cast<const bf16x8*>(B1b + boff[ni][1]);
    }
    if (stP) STAGE(Ag, A0b, m0, kt + 192);
    PRE_MFMA();
#pragma unroll
    for (int mi = 0; mi < 4; mi++)
#pragma unroll
      for (int ni = 0; ni < 2; ni++) {
        acc[0][1][mi][ni] = MFMA16(a[mi][0], b1[ni][0], acc[0][1][mi][ni]);
        acc[0][1][mi][ni] = MFMA16(a[mi][1], b1[ni][1], acc[0][1][mi][ni]);
      }
    POST_MFMA();

    // ---- ph7: Q(1,1): A1b; s7 = B0(t+3) ----
#pragma unroll
    for (int mi = 0; mi < 4; mi++) {
      a[mi][0] = *reinterpret_cast<const bf16x8*>(A1b + aoff[mi][0]);
      a[mi][1] = *reinterpret_cast<const bf16x8*>(A1b + aoff[mi][1]);
    }
    if (stP) STAGE(Bg, B0b, n0, kt + 192);
    PRE_MFMA();
#pragma unroll
    for (int mi = 0; mi < 4; mi++)
#pragma unroll
      for (int ni = 0; ni < 2; ni++) {
        acc[1][1][mi][ni] = MFMA16(a[mi][0], b1[ni][0], acc[1][1][mi][ni]);
        acc[1][1][mi][ni] = MFMA16(a[mi][1], b1[ni][1], acc[1][1][mi][ni]);
      }
    POST_MFMA();

    // ---- ph8: Q(1,0): no reads; s8 = B1(t+3); vmcnt ----
    if (stP) STAGE(Bg, B1b, n0 + 128, kt + 192);
    if (stP) asm volatile("s_waitcnt vmcnt(6)" ::: "memory");
    else     asm volatile("s_waitcnt vmcnt(0)" ::: "memory");
    PRE_MFMA();
#pragma unroll
    for (int mi = 0; mi < 4; mi++)
#pragma unroll
      for (int ni = 0; ni < 2; ni++) {
        acc[1][0][mi][ni] = MFMA16(a[mi][0], b0[ni][0], acc[1][0][mi][ni]);
        acc[1][0][mi][ni] = MFMA16(a[mi][1], b0[ni][1], acc[1][0][mi][ni]);
      }
    POST_MFMA();
  }
#undef STAGE
}

// ---------------- QKV projection + scatter + fused RoPE ----------------
__global__ __launch_bounds__(512, 2) void k_qkv(
    const unsigned short* __restrict__ xb,
    const unsigned short* __restrict__ wab,
    const float* __restrict__ tab,
    unsigned short* __restrict__ qr,
    unsigned short* __restrict__ kr,
    unsigned short* __restrict__ vt)
{
  __shared__ __align__(16) short lds[65536];
  f32x4 acc[2][2][4][2];
  int bid = blockIdx.x;                      // 768 blocks = 32 mt x 24 nt
  // mt-fastest XCD swizzle: each XCD owns mt rows [xcd*4, xcd*4+4) x all nt;
  // temporal window of 32 blocks shares 8 B-panels + 4 A-rows (12 MB) -> L2-fit.
  int xcd = bid & 7, idx = bid >> 3;         // idx 0..95
  int m0 = (xcd*4 + (idx & 3))*256;
  int n0 = (idx >> 2)*256;
  gemm256_core(xb, wab, m0, n0, lds, acc);

  int tid = threadIdx.x, wid = tid >> 6, lane = tid & 63;
  int wm = wid >> 2, wn = wid & 3, r15 = lane & 15, hi4 = lane >> 4;
  int which = n0 >> 11;            // 0=q, 1=k, 2=v (tiles never cross sections)
#pragma unroll
  for (int GM = 0; GM < 2; GM++) {
#pragma unroll
    for (int mi = 0; mi < 4; mi++) {
      int m_base = m0 + GM*128 + wm*64 + mi*16 + hi4*4;
      int b = m_base >> 11;
      int t0 = m_base & (TT - 1);
#pragma unroll
      for (int GN = 0; GN < 2; GN++) {
        int h = ((n0 & 2047) >> 7) + GN;
#pragma unroll
        for (int ni = 0; ni < 2; ni++) {
          int d = wn*32 + ni*16 + r15;
          if (which == 2) {
            ushort4 pv;
            pv.x = f2bf(acc[GM][GN][mi][ni][0]); pv.y = f2bf(acc[GM][GN][mi][ni][1]);
            pv.z = f2bf(acc[GM][GN][mi][ni][2]); pv.w = f2bf(acc[GM][GN][mi][ni][3]);
            *reinterpret_cast<ushort4*>(vt + ((size_t)((b*NHEAD + h)*HD + d))*TT + t0) = pv;
          } else {
            unsigned short* dst = (which == 0) ? qr : kr;
            size_t base = ((size_t)(b*NHEAD + h)*TT + t0)*HD + d;
            int j = d >> 1;
            bool odd = (d & 1);
#pragma unroll
            for (int r = 0; r < 4; r++) {
              float v = acc[GM][GN][mi][ni][r];
              float pv = __shfl_xor(v, 1);
              float2 cs = *reinterpret_cast<const float2*>(tab + ((size_t)(t0 + r)*64 + j)*2);
              float res = odd ? (pv*cs.y + v*cs.x) : (v*cs.x - pv*cs.y);
              dst[base + (size_t)r*HD] = f2bf(res);
            }
          }
        }
      }
    }
  }
}

// ---------------- output projection ----------------
__global__ __launch_bounds__(512, 2) void k_proj(
    const unsigned short* __restrict__ yb,
    const unsigned short* __restrict__ wpb,
    float* __restrict__ out)
{
  __shared__ __align__(16) short lds[65536];
  f32x4 acc[2][2][4][2];
  int bid = blockIdx.x;                      // 256 blocks = 32 mt x 8 nt
  int xcd = bid & 7, idx = bid >> 3;         // idx 0..31
  int m0 = (xcd*4 + (idx & 3))*256;
  int n0 = (idx >> 2)*256;
  gemm256_core(yb, wpb, m0, n0, lds, acc);

  int tid = threadIdx.x, wid = tid >> 6, lane = tid & 63;
  int wm = wid >> 2, wn = wid & 3, r15 = lane & 15, hi4 = lane >> 4;
#pragma unroll
  for (int GM = 0; GM < 2; GM++) {
#pragma unroll
    for (int mi = 0; mi < 4; mi++) {
      int m = m0 + GM*128 + wm*64 + mi*16 + hi4*4;
#pragma unroll
      for (int GN = 0; GN < 2; GN++) {
#pragma unroll
        for (int ni = 0; ni < 2; ni++) {
          int n = n0 + GN*128 + wn*32 + ni*16 + r15;
#pragma unroll
          for (int r = 0; r < 4; r++)
            out[(size_t)(m + r)*CC + n] = acc[GM][GN][mi][ni][r];
        }
      }
    }
  }
}

// ---------------- causal flash attention: swapped-QK^T 32x32, in-register softmax ----------------
// (unchanged from round 14/15 — 8-wave blocks, passed at absmax 0.015625)
__global__ __launch_bounds__(512, 1) void k_attn(
    const unsigned short* __restrict__ qr,
    const unsigned short* __restrict__ kr,
    const unsigned short* __restrict__ vt,
    unsigned short* __restrict__ yb)
{
  __shared__ __align__(16) short Ks[2][64*128];   // [buf][kv][d], chunk-XOR swizzled
  __shared__ __align__(16) short Vs[2][128*64];   // [buf][d][kv], chunk-XOR swizzled
  __shared__ float alds[8][32];                   // per-wave alpha/linv broadcast
  int bid = blockIdx.x;
  int bh = bid & 63, pr = bid >> 6;               // pr 0..3
  int tid = threadIdx.x, w = tid >> 6, lane = tid & 63;
  int l31 = lane & 31, hi = lane >> 5;
  const unsigned short* qg = qr + (size_t)bh*TT*HD;
  const unsigned short* kg = kr + (size_t)bh*TT*HD;
  const unsigned short* vg = vt + (size_t)bh*HD*TT;
  const float scale = 0.08838834764831845f; // 1/sqrt(128)
  int b = bh >> 4, h = bh & 15;

  int ksoff[2], vsoff[2];
#pragma unroll
  for (int i = 0; i < 2; i++) {
    int c = w*2 + i;
    int rK = c*4 + (lane >> 4);
    int cK = (lane & 15) ^ (rK & 7);
    ksoff[i] = rK*HD + cK*8;
    int dV = c*8 + (lane >> 3);
    int cV = (lane & 7) ^ (dV & 7);
    vsoff[i] = dV*TT + cV*8;
  }

#define STAGE_KV(BUF, KV0) do { \
    _Pragma("unroll") \
    for (int i_ = 0; i_ < 2; i_++) { \
      gl_lds16(kg + (size_t)(KV0)*HD + ksoff[i_], &Ks[BUF][(w*2 + i_)*512]); \
      gl_lds16(vg + (KV0) + vsoff[i_],            &Vs[BUF][(w*2 + i_)*512]); \
    } \
  } while(0)

#pragma unroll 1
  for (int ph = 0; ph < 2; ph++) {
    int qb = ph ? (7 - pr) : pr;
    int qlo = qb*256 + w*32;
    int qgi = qlo + l31;
    bf16x8 qf[8];
#pragma unroll
    for (int kk = 0; kk < 8; kk++)
      qf[kk] = *reinterpret_cast<const bf16x8*>(qg + (size_t)qgi*HD + kk*16 + hi*8);

    f32x16 ao[4];
#pragma unroll
    for (int dt = 0; dt < 4; dt++)
#pragma unroll
      for (int r = 0; r < 16; r++) ao[dt][r] = 0.f;
    float mrow = -3.0e38f, lsum = 0.f;
    int ntiles = 4*qb + 4;

    STAGE_KV(0, 0);
    __syncthreads();
    int cur = 0;

#pragma unroll 1
    for (int it = 0; it < ntiles; ++it) {
      int kv0 = it*64;
      if (it + 1 < ntiles) STAGE_KV(cur ^ 1, kv0 + 64);
      if (kv0 <= qlo + 31) {
        const short* Kc = Ks[cur];
        const short* Vc = Vs[cur];
        bool full = (kv0 + 63 <= qlo);
        f32x16 s0, s1;
#pragma unroll
        for (int r = 0; r < 16; r++) { s0[r] = 0.f; s1[r] = 0.f; }
        __builtin_amdgcn_s_setprio(1);
#pragma unroll
        for (int kk = 0; kk < 8; kk++) {
          int row0 = l31, row1 = 32 + l31;
          int ch0 = ((2*kk + hi) ^ (row0 & 7));
          int ch1 = ((2*kk + hi) ^ (row1 & 7));
          bf16x8 kf0 = *reinterpret_cast<const bf16x8*>((const char*)Kc + row0*256 + ch0*16);
          bf16x8 kf1 = *reinterpret_cast<const bf16x8*>((const char*)Kc + row1*256 + ch1*16);
          s0 = MFMA32(kf0, qf[kk], s0);
          s1 = MFMA32(kf1, qf[kk], s1);
        }
        __builtin_amdgcn_s_setprio(0);
        float p[32];
#pragma unroll
        for (int r = 0; r < 16; r++) {
          int kvl = (r & 3) + 8*(r >> 2) + 4*hi;
          float v0 = s0[r]*scale, v1 = s1[r]*scale;
          if (!full) {
            v0 = (kv0 + kvl      <= qgi) ? v0 : -3.0e38f;
            v1 = (kv0 + 32 + kvl <= qgi) ? v1 : -3.0e38f;
          }
          p[r] = v0; p[16 + r] = v1;
        }
        float t16[16];
#pragma unroll
        for (int i = 0; i < 16; i++) t16[i] = fmaxf(p[i], p[i + 16]);
#pragma unroll
        for (int i = 0; i < 8; i++) t16[i] = fmaxf(t16[i], t16[i + 8]);
#pragma unroll
        for (int i = 0; i < 4; i++) t16[i] = fmaxf(t16[i], t16[i + 4]);
        float mx = fmaxf(fmaxf(t16[0], t16[1]), fmaxf(t16[2], t16[3]));
        mx = fmaxf(mx, __shfl_xor(mx, 32));
        bool defer = __all(mx <= mrow + 8.f);
        if (!defer) {
          float mnew = fmaxf(mrow, mx);
          float alpha = __expf(mrow - mnew);
          mrow = mnew;
          lsum *= alpha;
          if (lane < 32) alds[w][lane] = alpha;
#pragma unroll
          for (int r = 0; r < 16; r++) {
            int ql = (r & 3) + 8*(r >> 2) + 4*hi;
            float av = alds[w][ql];
#pragma unroll
            for (int dt = 0; dt < 4; dt++) ao[dt][r] *= av;
          }
        }
#pragma unroll
        for (int i = 0; i < 32; i++) p[i] = __expf(p[i] - mrow);
#pragma unroll
        for (int i = 0; i < 16; i++) t16[i] = p[i] + p[i + 16];
#pragma unroll
        for (int i = 0; i < 8; i++) t16[i] = t16[i] + t16[i + 8];
#pragma unroll
        for (int i = 0; i < 4; i++) t16[i] = t16[i] + t16[i + 4];
        float rs = (t16[0] + t16[1]) + (t16[2] + t16[3]);
        rs += __shfl_xor(rs, 32);
        lsum += rs;
        bf16x8 pa[4];
#pragma unroll
        for (int ks = 0; ks < 4; ks++) {
          const int base = (ks >> 1)*16 + (ks & 1)*8;
          unsigned a0, a1, b0, b1;
          asm("v_cvt_pk_bf16_f32 %0, %1, %2" : "=v"(a0) : "v"(p[base + 0]), "v"(p[base + 1]));
          asm("v_cvt_pk_bf16_f32 %0, %1, %2" : "=v"(a1) : "v"(p[base + 2]), "v"(p[base + 3]));
          asm("v_cvt_pk_bf16_f32 %0, %1, %2" : "=v"(b0) : "v"(p[base + 4]), "v"(p[base + 5]));
          asm("v_cvt_pk_bf16_f32 %0, %1, %2" : "=v"(b1) : "v"(p[base + 6]), "v"(p[base + 7]));
          unsigned sa0 = (unsigned)__shfl_xor((int)a0, 32);
          unsigned sa1 = (unsigned)__shfl_xor((int)a1, 32);
          unsigned sb0 = (unsigned)__shfl_xor((int)b0, 32);
          unsigned sb1 = (unsigned)__shfl_xor((int)b1, 32);
          u32x4 pw;
          pw.x = hi ? sb0 : a0;
          pw.y = hi ? sb1 : a1;
          pw.z = hi ? b0 : sa0;
          pw.w = hi ? b1 : sa1;
          pa[ks] = __builtin_bit_cast(bf16x8, pw);
        }
        __builtin_amdgcn_s_setprio(1);
#pragma unroll
        for (int dt = 0; dt < 4; dt++) {
          int d = dt*32 + l31;
#pragma unroll
          for (int ks = 0; ks < 4; ks++) {
            int ch = ((2*ks + hi) ^ (d & 7));
            bf16x8 vf = *reinterpret_cast<const bf16x8*>((const char*)Vc + d*128 + ch*16);
            ao[dt] = MFMA32(pa[ks], vf, ao[dt]);
          }
        }
        __builtin_amdgcn_s_setprio(0);
      }
      __syncthreads();
      cur ^= 1;
    }
    if (lane < 32) alds[w][lane] = 1.0f / lsum;
#pragma unroll
    for (int r = 0; r < 16; r++) {
      int ql = (r & 3) + 8*(r >> 2) + 4*hi;
      float lv = alds[w][ql];
      int t = qlo + ql;
      size_t base = ((size_t)b*TT + t)*CC + h*HD + l31;
#pragma unroll
      for (int dt = 0; dt < 4; dt++)
        yb[base + dt*32] = f2bf(ao[dt][r] * lv);
    }
    __syncthreads();
  }
#undef STAGE_KV
}

extern "C" void kernel_launch(void* const* d_in, const int* in_sizes, int n_in,
                              void* d_out, int out_size, void* d_ws, size_t ws_size,
                              hipStream_t stream) {
  const float* x  = (const float*)d_in[0];
  const float* wa = (const float*)d_in[1];
  const float* wp = (const float*)d_in[2];
  float* out = (float*)d_out;
  char* ws = (char*)d_ws;
  size_t off = 0;
  unsigned short* xb  = (unsigned short*)(ws + off); off += (size_t)MTOT*CC*2;
  unsigned short* wab = (unsigned short*)(ws + off); off += (size_t)3*CC*CC*2;
  unsigned short* wpb = (unsigned short*)(ws + off); off += (size_t)CC*CC*2;
  unsigned short* qr  = (unsigned short*)(ws + off); off += (size_t)MTOT*CC*2;
  unsigned short* kr  = (unsigned short*)(ws + off); off += (size_t)MTOT*CC*2;
  unsigned short* vt  = (unsigned short*)(ws + off); off += (size_t)MTOT*CC*2;
  unsigned short* yb  = (unsigned short*)(ws + off); off += (size_t)MTOT*CC*2;
  float* tab          = (float*)(ws + off);          off += (size_t)TT*64*2*4;

  k_f2b<<<dim3(16384), dim3(256), 0, stream>>>(x,  xb,  MTOT*CC/4);
  k_f2b<<<dim3(12288), dim3(256), 0, stream>>>(wa, wab, 3*CC*CC/4);
  k_f2b<<<dim3(4096),  dim3(256), 0, stream>>>(wp, wpb, CC*CC/4);
  k_rope_tab<<<dim3(TT), dim3(64), 0, stream>>>(tab);
  k_qkv<<<dim3(768), dim3(512), 0, stream>>>(xb, wab, tab, qr, kr, vt);
  k_attn<<<dim3(256), dim3(512), 0, stream>>>(qr, kr, vt, yb);
  k_proj<<<dim3(256), dim3(512), 0, stream>>>(yb, wpb, out);
}